// Round 2
// baseline (629.208 us; speedup 1.0000x reference)
//
#include <hip/hip_runtime.h>

using u16 = unsigned short;
using u32 = unsigned int;
using short8 = __attribute__((ext_vector_type(8))) short;
using floatx4 = __attribute__((ext_vector_type(4))) float;
using floatx16 = __attribute__((ext_vector_type(16))) float;
using u32x4 = __attribute__((ext_vector_type(4))) u32;

__device__ __forceinline__ u32 fbits(float f) { union { float f; u32 u; } v; v.f = f; return v.u; }
__device__ __forceinline__ float fofb(u32 u) { union { u32 u; float f; } v; v.u = u; return v.f; }

__device__ __forceinline__ u16 f2bf(float f) {  // RNE
    u32 u = fbits(f);
    return (u16)((u + 0x7FFFu + ((u >> 16) & 1u)) >> 16);
}

// v_cvt_pk_bf16_f32: two fp32 -> packed 2xbf16 (RNE), lo=src0, hi=src1
__device__ __forceinline__ u32 cvtpk_bf16(float lo, float hi) {
    u32 r;
    asm("v_cvt_pk_bf16_f32 %0, %1, %2" : "=v"(r) : "v"(lo), "v"(hi));
    return r;
}

// split fp32 -> hi (truncated) + lo (residual, truncated); hi+lo error ~2^-17 rel
__device__ __forceinline__ void cvt_split8(const float* x, short8& h, short8& l) {
#pragma unroll
    for (int j = 0; j < 8; ++j) {
        u32 b = fbits(x[j]);
        h[j] = (short)(b >> 16);
        float r = x[j] - fofb(b & 0xffff0000u);
        l[j] = (short)(fbits(r) >> 16);
    }
}
__device__ __forceinline__ void cvt_rne8(const float* x, short8& h) {
#pragma unroll
    for (int j = 0; j < 8; ++j) h[j] = (short)f2bf(x[j]);
}

// async global->LDS, 16B per lane; LDS dest = wave-uniform base + lane*16
__device__ __forceinline__ void load_lds16(const void* g, u16* l) {
    __builtin_amdgcn_global_load_lds(
        (const __attribute__((address_space(1))) unsigned int*)(g),
        (__attribute__((address_space(3))) unsigned int*)(l), 16, 0, 0);
}

// ---------------- weight conversions fp32 -> bf16, 4 matrices in one launch ----
// DUP: matrices 0,1 (Wk,Wq) written duplicated along K: W2[n][2048] = [W|W],
// so the K=2048 hi/lo-split GEMM needs no in-loop B index games.
template<bool DUP>
__global__ void convw_kernel(const float* __restrict__ W0, const float* __restrict__ W1,
                             const float* __restrict__ W2, const float* __restrict__ W3,
                             u16* __restrict__ D0, u16* __restrict__ D1,
                             u16* __restrict__ D2, u16* __restrict__ D3) {
    int y = blockIdx.y;
    const float* s = (y == 0) ? W0 : (y == 1) ? W1 : (y == 2) ? W2 : W3;
    u16* d = (y == 0) ? D0 : (y == 1) ? D1 : (y == 2) ? D2 : D3;
    int i = (blockIdx.x * 256 + threadIdx.x) * 4;
    float4 v = *reinterpret_cast<const float4*>(s + i);
    ushort4 h;
    h.x = f2bf(v.x); h.y = f2bf(v.y); h.z = f2bf(v.z); h.w = f2bf(v.w);
    if (DUP && y < 2) {
        int n = i >> 10, k = i & 1023;
        u16* base = d + (size_t)n * 2048 + k;
        *reinterpret_cast<ushort4*>(base) = h;
        *reinterpret_cast<ushort4*>(base + 1024) = h;
    } else {
        *reinterpret_cast<ushort4*>(d + i) = h;
    }
}

// ---------------- activation conversion fp32 -> bf16 ---------------------------
// SPLIT: X[m][1024] fp32 -> O[m][2048] bf16 with [0:1024]=hi(trunc),
// [1024:2048]=lo(trunc residual) — exact same values as the old in-loop
// cvt_split8, hoisted out of the GEMM K-loop (removes ~180 VALU/K-step there).
template<bool SPLIT>
__global__ __launch_bounds__(256)
void convx_kernel(const float* __restrict__ X, u16* __restrict__ O) {
    int i = (blockIdx.x * 256 + threadIdx.x) * 4;
    float4 v = *reinterpret_cast<const float4*>(X + i);
    if (SPLIT) {
        int m = i >> 10, k = i & 1023;
        float xs[4] = {v.x, v.y, v.z, v.w};
        ushort4 h, l;
        u16 hh[4], ll[4];
#pragma unroll
        for (int j = 0; j < 4; ++j) {
            u32 b = fbits(xs[j]);
            hh[j] = (u16)(b >> 16);
            float r = xs[j] - fofb(b & 0xffff0000u);
            ll[j] = (u16)(fbits(r) >> 16);
        }
        h.x = hh[0]; h.y = hh[1]; h.z = hh[2]; h.w = hh[3];
        l.x = ll[0]; l.y = ll[1]; l.z = ll[2]; l.w = ll[3];
        *reinterpret_cast<ushort4*>(O + (size_t)m * 2048 + k) = h;
        *reinterpret_cast<ushort4*>(O + (size_t)m * 2048 + 1024 + k) = l;
    } else {
        ushort4 h;
        h.x = f2bf(v.x); h.y = f2bf(v.y); h.z = f2bf(v.z); h.w = f2bf(v.w);
        *reinterpret_cast<ushort4*>(O + i) = h;
    }
}

// ---------------- GEMM: C[M,N] = A[M,K] @ B[N,K]^T  (fp32 acc) --------------------
// 128x128 tile, BK=32, 256 threads (4 waves, 64x64/wave), global_load_lds staging.
// Grid is (M/128, N/128): linear-block-id % 8 == bm-idx % 8, so the 8 blocks
// sharing one A-row-slice land on ONE XCD (round-robin heuristic) -> A L2 reuse.
// KDIM: row stride / K extent (2048 for the pre-split hi|lo GEMMs).
// FP32A (legacy fallback): A staged as fp32, converted at fragment read.
// SPLIT (legacy, implies FP32A): 2-term C ~= Ah*B + Al*B.
// TRANS: write transposed per (b,h): Vt[(b*8+h)*128 + d][l].
// POOL: no C write; per-column sum/max partials over the block's 128 rows.
#define GN 1024

template<int KDIM, bool SPLIT, bool TRANS, bool POOL, bool FP32A>
__global__ __launch_bounds__(256)
void gemm_bt(const void* __restrict__ Av, const u16* __restrict__ Bh,
             u16* __restrict__ Cb, float scale, u16* __restrict__ Vt,
             float* __restrict__ psum, float* __restrict__ pmax)
{
    constexpr int SM = TRANS ? 17408 : (FP32A ? 12288 : 8192);
    __shared__ __align__(16) u16 smem[SM];

    const int tid  = threadIdx.x;
    const int lane = tid & 63, wave = tid >> 6;
    const int quad = lane >> 4, l15 = lane & 15;
    const int wr = wave >> 1, wc = wave & 1;
    const int bm = blockIdx.x * 128, bn = blockIdx.y * 128;

    const int BOff = FP32A ? 8192 : 4096;   // u16 offset of B region

    floatx4 acc[4][4];
#pragma unroll
    for (int mt = 0; mt < 4; ++mt)
#pragma unroll
        for (int nt = 0; nt < 4; ++nt)
#pragma unroll
            for (int r = 0; r < 4; ++r) acc[mt][nt][r] = 0.f;

    const int s8 = (quad ^ ((l15 >> 1) & 3)) * 8;   // bf16 fragment chunk swizzle

    for (int kt = 0; kt < KDIM; kt += 32) {
        __syncthreads();
        if (FP32A) {
            // A: 16 issues x 8 fp32-rows (1 KB); B: 8 issues x 16 bf16-rows
            const float* Af = (const float*)Av;
            const int arow = lane >> 3, achk = (lane & 7) ^ (lane >> 3);
            const int brow = lane >> 2, bchk = (lane & 3) ^ ((lane >> 3) & 3);
#pragma unroll
            for (int j = 0; j < 6; ++j) {
                int n = wave + 4 * j;
                if (n < 16) {
                    load_lds16(Af + (size_t)(bm + n * 8 + arow) * KDIM + kt + achk * 4,
                               smem + n * 512);
                } else {
                    int m = n - 16;
                    load_lds16(Bh + (size_t)(bn + m * 16 + brow) * KDIM + kt + bchk * 8,
                               smem + 8192 + m * 512);
                }
            }
        } else {
            const u16* Ab = (const u16*)Av;
            const int cgl = (lane & 3) ^ ((lane >> 3) & 3);
            const int rl  = lane >> 2;
            const u16* gp = (wave < 2) ? Ab : Bh;
            int rowb = (wave < 2) ? bm : bn;
            u16* lp = smem + (wave >> 1) * 4096;
            int q0 = (wave & 1) * 4;
#pragma unroll
            for (int q = 0; q < 4; ++q) {
                int qq = q0 + q;
                load_lds16(gp + (size_t)(rowb + qq * 16 + rl) * KDIM + cgl * 8 + kt,
                           lp + qq * 512);
            }
        }
        __syncthreads();

        short8 a_h[4], a_l[4], b_h[4];
        if (FP32A) {
            const float* Af4 = (const float*)smem;
#pragma unroll
            for (int mt = 0; mt < 4; ++mt) {
                int ra = wr * 64 + mt * 16 + l15;
                int f = ra & 7;
                float xv[8];
                *reinterpret_cast<float4*>(xv) =
                    *reinterpret_cast<const float4*>(Af4 + ra * 32 + (((2 * quad) ^ f) * 4));
                *reinterpret_cast<float4*>(xv + 4) =
                    *reinterpret_cast<const float4*>(Af4 + ra * 32 + (((2 * quad + 1) ^ f) * 4));
                if (SPLIT) cvt_split8(xv, a_h[mt], a_l[mt]);
                else       cvt_rne8(xv, a_h[mt]);
            }
        } else {
#pragma unroll
            for (int mt = 0; mt < 4; ++mt) {
                int ra = wr * 64 + mt * 16 + l15;
                a_h[mt] = *reinterpret_cast<const short8*>(smem + ra * 32 + s8);
            }
        }
#pragma unroll
        for (int nt = 0; nt < 4; ++nt) {
            int rb = wc * 64 + nt * 16 + l15;
            b_h[nt] = *reinterpret_cast<const short8*>(smem + BOff + rb * 32 + s8);
        }
#pragma unroll
        for (int mt = 0; mt < 4; ++mt)
#pragma unroll
            for (int nt = 0; nt < 4; ++nt)
                acc[mt][nt] = __builtin_amdgcn_mfma_f32_16x16x32_bf16(a_h[mt], b_h[nt], acc[mt][nt], 0, 0, 0);
        if (SPLIT) {
#pragma unroll
            for (int mt = 0; mt < 4; ++mt)
#pragma unroll
                for (int nt = 0; nt < 4; ++nt)
                    acc[mt][nt] = __builtin_amdgcn_mfma_f32_16x16x32_bf16(a_l[mt], b_h[nt], acc[mt][nt], 0, 0, 0);
        }
    }

    if (POOL) {
#pragma unroll
        for (int nt = 0; nt < 4; ++nt) {
            float s = 0.f, m = -3.0e38f;
#pragma unroll
            for (int mt = 0; mt < 4; ++mt)
#pragma unroll
                for (int r = 0; r < 4; ++r) {
                    float v = acc[mt][nt][r];
                    s += v; m = fmaxf(m, v);
                }
            s += __shfl_xor(s, 16); s += __shfl_xor(s, 32);
            m = fmaxf(m, __shfl_xor(m, 16)); m = fmaxf(m, __shfl_xor(m, 32));
            if (quad == 0) {
                int col = bn + wc * 64 + nt * 16 + l15;
                int chunk = (bm >> 6) + wr;   // rows bm+wr*64 .. +63
                psum[chunk * 1024 + col] = s;
                pmax[chunk * 1024 + col] = m;
            }
        }
    } else if (!TRANS) {
#pragma unroll
        for (int mt = 0; mt < 4; ++mt)
#pragma unroll
            for (int nt = 0; nt < 4; ++nt)
#pragma unroll
                for (int r = 0; r < 4; ++r) {
                    int row = bm + wr * 64 + mt * 16 + quad * 4 + r;
                    int col = bn + wc * 64 + nt * 16 + l15;
                    Cb[(size_t)row * GN + col] = f2bf(acc[mt][nt][r] * scale);
                }
    } else {
        __syncthreads();
#pragma unroll
        for (int mt = 0; mt < 4; ++mt)
#pragma unroll
            for (int nt = 0; nt < 4; ++nt)
#pragma unroll
                for (int r = 0; r < 4; ++r) {
                    int row_local = wr * 64 + mt * 16 + quad * 4 + r;
                    int col_local = wc * 64 + nt * 16 + l15;
                    smem[col_local * 136 + row_local] = f2bf(acc[mt][nt][r]);
                }
        __syncthreads();
        int b = bm >> 10, l0 = bm & 1023, h = bn >> 7;
        int d = tid >> 1, rblk = (tid & 1) * 64;
        u16* gv = Vt + ((size_t)(b * 8 + h) * 128 + d) * 1024 + l0 + rblk;
#pragma unroll
        for (int v = 0; v < 8; ++v)
            *reinterpret_cast<short8*>(gv + v * 8) =
                *reinterpret_cast<const short8*>(smem + d * 136 + rblk + v * 8);
    }
}

// ---------------- fused flash attention (no-max softmax, 32x32 MFMA) -------------
// grid (8,8,16) REMAPPED inside: lin = bx + 8*by + 64*bz; qt = lin>>7 (slowest),
// hd = lin&7, b = (lin>>3)&15.  All 8 qt-blocks sharing one (b,h) K/V stripe have
// lin%8 == hd -> same XCD -> K/V stays L2-resident (T1).
// Double-buffered K/V LDS; P fully in registers via cvt_pk + permlane32_swap.
#define LOG2E 1.44269504088896f
#define EXPC  46.1662413084470f   // 32 * log2(e)

__global__ __launch_bounds__(256, 2)
void attn_kernel(const u16* __restrict__ Q, const u16* __restrict__ Kk,
                 const u16* __restrict__ Vt, u16* __restrict__ AO)
{
    __shared__ __align__(16) u16 Ks[2][64 * 128];    // [key][d], slot c = c ^ (key&7)
    __shared__ __align__(16) u16 Vts[2][128 * 64];   // [d][key], slot c = c ^ (d&7)

    const int tid  = threadIdx.x;
    const int lane = tid & 63, wave = tid >> 6;
    const int l31 = lane & 31, h2 = lane >> 5;    // 32-row index, k-half
    const int l7 = lane & 7;                      // == l31 & 7

    // XCD swizzle: qt slowest-varying (see header comment)
    const int lin = blockIdx.x + (blockIdx.y << 3) + (blockIdx.z << 6);
    const int qt = lin >> 7;
    const int hd = lin & 7;
    const int b  = (lin >> 3) & 15;

    // Q fragments: B-operand, n = q = l31 (wave's 32 q), k = s*16 + h2*8 + j
    short8 qf[8];
    {
        int qrow = b * 1024 + qt * 128 + wave * 32 + l31;
        const u16* qp = Q + (size_t)qrow * 1024 + hd * 128 + h2 * 8;
#pragma unroll
        for (int s = 0; s < 8; ++s)
            qf[s] = *reinterpret_cast<const short8*>(qp + s * 16);
    }

    float lsum = 0.f;        // per lane: q = l31, keys of half h2
    floatx16 oacc[4];        // O[q 32][d db*32+l31], D-layout
#pragma unroll
    for (int db = 0; db < 4; ++db)
#pragma unroll
        for (int r = 0; r < 16; ++r) oacc[db][r] = 0.f;

    // staging bases (LDS slot c holds global chunk c ^ (row&7))
    const int krow_l = lane >> 4;
    const u16* kgB[4];
#pragma unroll
    for (int i = 0; i < 4; ++i) {
        int cg = (lane & 15) ^ ((i * 4 + krow_l) & 7);
        kgB[i] = Kk + (size_t)(b * 1024 + wave * 16 + i * 4 + krow_l) * 1024
                    + hd * 128 + cg * 8;
    }
    const u16* vtb = Vt + (size_t)(b * 8 + hd) * 128 * 1024;
    const int vrow_l = lane >> 3;
    const u16* vgB = vtb + (size_t)(wave * 32 + vrow_l) * 1024
                         + (((lane & 7) ^ vrow_l) * 8);

    // prologue: stage tile 0 into buffer 0
#pragma unroll
    for (int i = 0; i < 4; ++i)
        load_lds16(kgB[i], &Ks[0][(wave * 16 + i * 4) * 128]);
#pragma unroll
    for (int i = 0; i < 4; ++i)
        load_lds16(vgB + (size_t)i * 8 * 1024, &Vts[0][(wave * 32 + i * 8) * 64]);

    for (int t = 0; t < 16; ++t) {
        const int cur = t & 1;
        // own tile-t loads done before signaling; barrier -> all waves' loads done
        asm volatile("s_waitcnt vmcnt(0)" ::: "memory");
        __builtin_amdgcn_s_barrier();
        __builtin_amdgcn_sched_barrier(0);
        if (t < 15) {   // prefetch tile t+1 into the other buffer (safe: all waves
                        // finished reading it for tile t-1 before barrier above)
            const int nxt = cur ^ 1;
#pragma unroll
            for (int i = 0; i < 4; ++i)
                load_lds16(kgB[i] + (size_t)(t + 1) * 64 * 1024,
                           &Ks[nxt][(wave * 16 + i * 4) * 128]);
#pragma unroll
            for (int i = 0; i < 4; ++i)
                load_lds16(vgB + (size_t)i * 8 * 1024 + (size_t)(t + 1) * 64,
                           &Vts[nxt][(wave * 32 + i * 8) * 64]);
        }
        const u16* ksb = Ks[cur];
        const u16* vsb = Vts[cur];

        // S^T + in-register softmax/pack per 32-key block
        short8 pfr[4];   // PV A-fragments for the tile's 4 ksteps of 16 keys
#pragma unroll
        for (int kb = 0; kb < 2; ++kb) {
            floatx16 sacc;
#pragma unroll
            for (int r = 0; r < 16; ++r) sacc[r] = 0.f;
            __builtin_amdgcn_s_setprio(1);
#pragma unroll
            for (int s = 0; s < 8; ++s) {
                short8 kfr = *reinterpret_cast<const short8*>(
                    &ksb[(kb * 32 + l31) * 128 + (((s * 2 + h2) ^ l7) * 8)]);
                sacc = __builtin_amdgcn_mfma_f32_32x32x16_bf16(kfr, qf[s], sacc, 0, 0, 0);
            }
            __builtin_amdgcn_s_setprio(0);
            // lane holds P[key = kb*32 + 8*(r>>2) + 4*h2 + (r&3)][q = l31]
#pragma unroll
            for (int r = 0; r < 16; ++r) {
                float p = exp2f(fmaf(sacc[r], LOG2E, -EXPC));
                sacc[r] = p;
                lsum += p;
            }
            // pack per quad qd: c0 = keys {8qd+4h2+0,1}, c1 = {8qd+4h2+2,3}
            u32 c0[4], c1[4];
#pragma unroll
            for (int qd = 0; qd < 4; ++qd) {
                c0[qd] = cvtpk_bf16(sacc[4 * qd + 0], sacc[4 * qd + 1]);
                c1[qd] = cvtpk_bf16(sacc[4 * qd + 2], sacc[4 * qd + 3]);
            }
#pragma unroll
            for (int pb = 0; pb < 2; ++pb) {
                auto r1a = __builtin_amdgcn_permlane32_swap(c0[2 * pb],     c1[2 * pb],     false, false);
                auto r2a = __builtin_amdgcn_permlane32_swap(c1[2 * pb],     c0[2 * pb],     false, false);
                auto r1b = __builtin_amdgcn_permlane32_swap(c0[2 * pb + 1], c1[2 * pb + 1], false, false);
                auto r2b = __builtin_amdgcn_permlane32_swap(c1[2 * pb + 1], c0[2 * pb + 1], false, false);
                u32 w0 = h2 ? (u32)r2b[0] : (u32)r1a[0];
                u32 w1 = h2 ? (u32)r1b[0] : (u32)r2a[0];
                u32 w2 = h2 ? (u32)r2b[1] : (u32)r1a[1];
                u32 w3 = h2 ? (u32)r1b[1] : (u32)r2a[1];
                u32x4 ww = {w0, w1, w2, w3};
                pfr[kb * 2 + pb] = __builtin_bit_cast(short8, ww);
            }
        }

        // O += P V: A = P[q][key] (regs), B = Vt[d][key]; 4 ksteps of 16 keys
        __builtin_amdgcn_s_setprio(1);
#pragma unroll
        for (int ks = 0; ks < 4; ++ks) {
#pragma unroll
            for (int db = 0; db < 4; ++db) {
                int d = db * 32 + l31;
                short8 vfr = *reinterpret_cast<const short8*>(
                    &vsb[d * 64 + (((ks * 2 + h2) ^ l7) * 8)]);
                oacc[db] = __builtin_amdgcn_mfma_f32_32x32x16_bf16(pfr[ks], vfr, oacc[db], 0, 0, 0);
            }
        }
        __builtin_amdgcn_s_setprio(0);
    }

    // combine key-halves: lane q=l31 (both h2) -> full row sum
    lsum += __shfl_xor(lsum, 32);

    // epilogue: O row q = 8*rg + 4*h2 + r, col d = db*32 + l31
    int qbase = b * 1024 + qt * 128 + wave * 32;
#pragma unroll
    for (int rg = 0; rg < 4; ++rg)
#pragma unroll
        for (int r = 0; r < 4; ++r) {
            int row = rg * 8 + 4 * h2 + r;
            float inv = 1.0f / __shfl(lsum, row);
            u16* ao = AO + (size_t)(qbase + row) * 1024 + hd * 128 + l31;
#pragma unroll
            for (int db = 0; db < 4; ++db)
                ao[db * 32] = f2bf(oacc[db][rg * 4 + r] * inv);
        }
}

// ---------------- fused pooling-combine + MLP head ------------------------------
__global__ __launch_bounds__(256)
void head_kernel(const float* __restrict__ psum, const float* __restrict__ pmax,
                 const float* __restrict__ bu, const float* __restrict__ Wmlp,
                 const float* __restrict__ bmlp, float* __restrict__ out) {
    __shared__ float pool_s[1024];
    int b = blockIdx.x, tid = threadIdx.x;
    int c4 = tid * 4;
    float4 s = {0.f, 0.f, 0.f, 0.f};
    float4 m = {-3.0e38f, -3.0e38f, -3.0e38f, -3.0e38f};
#pragma unroll
    for (int c = 0; c < 16; ++c) {
        float4 a = *reinterpret_cast<const float4*>(psum + (size_t)(b * 16 + c) * 1024 + c4);
        float4 x = *reinterpret_cast<const float4*>(pmax + (size_t)(b * 16 + c) * 1024 + c4);
        s.x += a.x; s.y += a.y; s.z += a.z; s.w += a.w;
        m.x = fmaxf(m.x, x.x); m.y = fmaxf(m.y, x.y);
        m.z = fmaxf(m.z, x.z); m.w = fmaxf(m.w, x.w);
    }
    float4 bb = *reinterpret_cast<const float4*>(bu + c4);
    pool_s[c4 + 0] = s.x * (1.0f / 1024.0f) + m.x + 2.0f * bb.x;
    pool_s[c4 + 1] = s.y * (1.0f / 1024.0f) + m.y + 2.0f * bb.y;
    pool_s[c4 + 2] = s.z * (1.0f / 1024.0f) + m.z + 2.0f * bb.z;
    pool_s[c4 + 3] = s.w * (1.0f / 1024.0f) + m.w + 2.0f * bb.w;
    __syncthreads();
    int o = tid >> 2, seg = tid & 3;
    const float4* wr = reinterpret_cast<const float4*>(Wmlp + o * 1024 + seg * 256);
    const float4* pr = reinterpret_cast<const float4*>(pool_s + seg * 256);
    float acc = 0.f;
#pragma unroll 8
    for (int i = 0; i < 64; ++i) {
        float4 a = pr[i], w = wr[i];
        acc += a.x * w.x + a.y * w.y + a.z * w.z + a.w * w.w;
    }
    acc += __shfl_xor(acc, 1);
    acc += __shfl_xor(acc, 2);
    if (seg == 0) out[b * 64 + o] = acc + bmlp[o];
}

extern "C" void kernel_launch(void* const* d_in, const int* in_sizes, int n_in,
                              void* d_out, int out_size, void* d_ws, size_t ws_size,
                              hipStream_t stream) {
    const float* x0 = (const float*)d_in[0];
    const float* x1 = (const float*)d_in[1];
    const float* x2 = (const float*)d_in[2];
    const float* Wk = (const float*)d_in[5];
    const float* Wq = (const float*)d_in[6];
    const float* Wv = (const float*)d_in[7];
    const float* Wu = (const float*)d_in[8];
    const float* bu = (const float*)d_in[9];
    const float* Wmlp = (const float*)d_in[10];
    const float* bmlp = (const float*)d_in[11];
    float* out = (float*)d_out;

    char* ws = (char*)d_ws;
    const size_t MB = 1048576ull;
    const float scale = 0.29730177875068026f;  // 128^(-0.25)

    // ---- new path: pre-split activations, pure-bf16 GEMMs. 140 MB workspace ----
    // layout: [Wk2 4M][Wq2 4M][Wvh 2M][Wuh 2M][XS 64M][Qb 32M][Kb 32M]
    // XS reuse timeline: x2 hi|lo -> x1 hi|lo -> { x0h (0:32M) , Vt (32:64M) }
    //                    -> AOb (0:32M, Vt still live at 32:64M).
    // psum/pmax overlay Qb (dead after attn).
    const size_t wo_new = 4 * MB + 4 * MB + 2 * MB + 2 * MB + 64 * MB + 32 * MB + 32 * MB;
    if (ws_size >= wo_new) {
        u16* Wk2 = (u16*)(ws);
        u16* Wq2 = (u16*)(ws + 4 * MB);
        u16* Wvh = (u16*)(ws + 8 * MB);
        u16* Wuh = (u16*)(ws + 10 * MB);
        u16* XS  = (u16*)(ws + 12 * MB);
        u16* Qb  = (u16*)(ws + 76 * MB);
        u16* Kb  = (u16*)(ws + 108 * MB);
        u16* Vt  = XS + 16 * MB;          // u16 units: +32 MB bytes
        u16* AOb = XS;
        float* psum = (float*)Qb;
        float* pmax = (float*)((char*)Qb + 1 * MB);

        convw_kernel<true><<<dim3(1024, 4), 256, 0, stream>>>(Wk, Wq, Wv, Wu, Wk2, Wq2, Wvh, Wuh);

        dim3 ggrid(128, 8);  // (M/128, N/128): same-A blocks share an XCD

        // q = (x2 @ Wk^T) * scale : pre-split A, K=2048 pure-bf16
        convx_kernel<true><<<16384, 256, 0, stream>>>(x2, XS);
        gemm_bt<2048, false, false, false, false><<<ggrid, 256, 0, stream>>>(XS, Wk2, Qb, scale, nullptr, nullptr, nullptr);
        // k = (x1 @ Wq^T) * scale
        convx_kernel<true><<<16384, 256, 0, stream>>>(x1, XS);
        gemm_bt<2048, false, false, false, false><<<ggrid, 256, 0, stream>>>(XS, Wq2, Kb, scale, nullptr, nullptr, nullptr);
        // v = x0 @ Wv^T, written transposed per (b,h); A = rne bf16 at XS[0:32M]
        convx_kernel<false><<<16384, 256, 0, stream>>>(x0, XS);
        gemm_bt<1024, false, true, false, false><<<ggrid, 256, 0, stream>>>(XS, Wvh, nullptr, 1.0f, Vt, nullptr, nullptr);

        dim3 agrid(8, 8, 16);  // remapped in-kernel: qt slowest for XCD K/V locality
        attn_kernel<<<agrid, 256, 0, stream>>>(Qb, Kb, Vt, AOb);

        gemm_bt<1024, false, false, true, false><<<ggrid, 256, 0, stream>>>(AOb, Wuh, nullptr, 1.0f, nullptr, psum, pmax);

        head_kernel<<<16, 256, 0, stream>>>(psum, pmax, bu, Wmlp, bmlp, out);
        return;
    }

    // ---- fallback: round-1 path (138 MB) --------------------------------------
    const size_t MB32 = 33554432ull;
    size_t wo = 0;
    u16* Wkh = (u16*)(ws + wo); wo += 2097152;
    u16* Wqh = (u16*)(ws + wo); wo += 2097152;
    u16* Wvh = (u16*)(ws + wo); wo += 2097152;
    u16* Wuh = (u16*)(ws + wo); wo += 2097152;
    u16* Qb = (u16*)(ws + wo); wo += MB32;
    u16* Kb = (u16*)(ws + wo); wo += MB32;
    u16* Vt = (u16*)(ws + wo); wo += MB32;
    u16* AOb = (u16*)(ws + wo); wo += MB32;
    float* psum = (float*)(ws + wo); wo += 1048576;   // [256][1024]
    float* pmax = (float*)(ws + wo); wo += 1048576;
    if (ws_size < wo) return;

    convw_kernel<false><<<dim3(1024, 4), 256, 0, stream>>>(Wk, Wq, Wv, Wu, Wkh, Wqh, Wvh, Wuh);

    dim3 ggrid(128, 8);
    gemm_bt<1024, true, false, false, true><<<ggrid, 256, 0, stream>>>(x2, Wkh, Qb, scale, nullptr, nullptr, nullptr);
    gemm_bt<1024, true, false, false, true><<<ggrid, 256, 0, stream>>>(x1, Wqh, Kb, scale, nullptr, nullptr, nullptr);
    gemm_bt<1024, false, true, false, true><<<ggrid, 256, 0, stream>>>(x0, Wvh, nullptr, 1.0f, Vt, nullptr, nullptr);

    dim3 agrid(8, 8, 16);
    attn_kernel<<<agrid, 256, 0, stream>>>(Qb, Kb, Vt, AOb);

    gemm_bt<1024, false, false, true, false><<<ggrid, 256, 0, stream>>>(AOb, Wuh, nullptr, 1.0f, nullptr, psum, pmax);

    head_kernel<<<16, 256, 0, stream>>>(psum, pmax, bu, Wmlp, bmlp, out);
}

// Round 4
// 592.911 us; speedup vs baseline: 1.0612x; 1.0612x over previous
//
#include <hip/hip_runtime.h>

using u16 = unsigned short;
using u32 = unsigned int;
using short8 = __attribute__((ext_vector_type(8))) short;
using floatx4 = __attribute__((ext_vector_type(4))) float;
using floatx16 = __attribute__((ext_vector_type(16))) float;
using u32x4 = __attribute__((ext_vector_type(4))) u32;

__device__ __forceinline__ u32 fbits(float f) { union { float f; u32 u; } v; v.f = f; return v.u; }
__device__ __forceinline__ float fofb(u32 u) { union { u32 u; float f; } v; v.u = u; return v.f; }

__device__ __forceinline__ u16 f2bf(float f) {  // RNE
    u32 u = fbits(f);
    return (u16)((u + 0x7FFFu + ((u >> 16) & 1u)) >> 16);
}

// v_cvt_pk_bf16_f32: two fp32 -> packed 2xbf16 (RNE), lo=src0, hi=src1
__device__ __forceinline__ u32 cvtpk_bf16(float lo, float hi) {
    u32 r;
    asm("v_cvt_pk_bf16_f32 %0, %1, %2" : "=v"(r) : "v"(lo), "v"(hi));
    return r;
}

// split fp32 -> hi (truncated) + lo (residual, truncated); hi+lo error ~2^-17 rel
__device__ __forceinline__ void cvt_split8(const float* x, short8& h, short8& l) {
#pragma unroll
    for (int j = 0; j < 8; ++j) {
        u32 b = fbits(x[j]);
        h[j] = (short)(b >> 16);
        float r = x[j] - fofb(b & 0xffff0000u);
        l[j] = (short)(fbits(r) >> 16);
    }
}
__device__ __forceinline__ void cvt_rne8(const float* x, short8& h) {
#pragma unroll
    for (int j = 0; j < 8; ++j) h[j] = (short)f2bf(x[j]);
}

// async global->LDS, 16B per lane; LDS dest = wave-uniform base + lane*16
__device__ __forceinline__ void load_lds16(const void* g, u16* l) {
    __builtin_amdgcn_global_load_lds(
        (const __attribute__((address_space(1))) unsigned int*)(g),
        (__attribute__((address_space(3))) unsigned int*)(l), 16, 0, 0);
}

// raw barrier WITH memory clobber: orders all memory ops (ds_read, global_load_lds)
// across it but does NOT drain counters (unlike __syncthreads).
__device__ __forceinline__ void barrier_mem() {
    asm volatile("s_barrier" ::: "memory");
}
#define WAITVM(N) asm volatile("s_waitcnt vmcnt(" #N ")" ::: "memory")

// ---------------- weight conversions fp32 -> bf16, 4 matrices in one launch ----
// DUP: matrices 0,1 (Wk,Wq) written duplicated along K: W2[n][2048] = [W|W].
template<bool DUP>
__global__ void convw_kernel(const float* __restrict__ W0, const float* __restrict__ W1,
                             const float* __restrict__ W2, const float* __restrict__ W3,
                             u16* __restrict__ D0, u16* __restrict__ D1,
                             u16* __restrict__ D2, u16* __restrict__ D3) {
    int y = blockIdx.y;
    const float* s = (y == 0) ? W0 : (y == 1) ? W1 : (y == 2) ? W2 : W3;
    u16* d = (y == 0) ? D0 : (y == 1) ? D1 : (y == 2) ? D2 : D3;
    int i = (blockIdx.x * 256 + threadIdx.x) * 4;
    float4 v = *reinterpret_cast<const float4*>(s + i);
    ushort4 h;
    h.x = f2bf(v.x); h.y = f2bf(v.y); h.z = f2bf(v.z); h.w = f2bf(v.w);
    if (DUP && y < 2) {
        int n = i >> 10, k = i & 1023;
        u16* base = d + (size_t)n * 2048 + k;
        *reinterpret_cast<ushort4*>(base) = h;
        *reinterpret_cast<ushort4*>(base + 1024) = h;
    } else {
        *reinterpret_cast<ushort4*>(d + i) = h;
    }
}

// ---------------- activation conversion fp32 -> bf16 ---------------------------
// SPLIT: X[m][1024] fp32 -> O[m][2048] bf16, [0:1024]=hi(trunc), [1024:2048]=lo.
template<bool SPLIT>
__global__ __launch_bounds__(256)
void convx_kernel(const float* __restrict__ X, u16* __restrict__ O) {
    int i = (blockIdx.x * 256 + threadIdx.x) * 4;
    float4 v = *reinterpret_cast<const float4*>(X + i);
    if (SPLIT) {
        int m = i >> 10, k = i & 1023;
        float xs[4] = {v.x, v.y, v.z, v.w};
        ushort4 h, l;
        u16 hh[4], ll[4];
#pragma unroll
        for (int j = 0; j < 4; ++j) {
            u32 b = fbits(xs[j]);
            hh[j] = (u16)(b >> 16);
            float r = xs[j] - fofb(b & 0xffff0000u);
            ll[j] = (u16)(fbits(r) >> 16);
        }
        h.x = hh[0]; h.y = hh[1]; h.z = hh[2]; h.w = hh[3];
        l.x = ll[0]; l.y = ll[1]; l.z = ll[2]; l.w = ll[3];
        *reinterpret_cast<ushort4*>(O + (size_t)m * 2048 + k) = h;
        *reinterpret_cast<ushort4*>(O + (size_t)m * 2048 + 1024 + k) = l;
    } else {
        ushort4 h;
        h.x = f2bf(v.x); h.y = f2bf(v.y); h.z = f2bf(v.z); h.w = f2bf(v.w);
        *reinterpret_cast<ushort4*>(O + i) = h;
    }
}

// ================= 256x256 8-wave counted-vmcnt GEMM (T2+T3+T4+T5) ==============
// C[M,1024] = A[M,KDIM] @ B[1024,KDIM]^T, bf16 in, bf16 out (scaled).
// 512 thr = 8 waves (2M x 4N), per-wave C = 128x64 (acc[8][4] 16x16 frags).
// LDS: dbuf x (A 256x64 + B 256x64) bf16 = 128 KiB (dynamic).
// Per K-tile (BK=64): 4 quadrant-phases x {ds_read frags; stage issue; barrier;
// setprio(1); 16 MFMA; setprio(0); barrier}.  Stage protocol (per wave, per tile
// 8 global_load_lds instrs = 4 half-tiles x 2):
//   t.P0: issue t+1.h2 ; t.P1: t+1.h3 ;
//   t.P3 (after MFMA): t+2.h0,h1 ; then s_waitcnt vmcnt(4) ; final barrier.
// Queue at t.P3 wait: [t+1.h0..h3 (8), t+2.h0,h1 (4)] -> vmcnt(4) completes all
// of t+1 (oldest-first), keeps 4 in flight. Never drains to 0 in steady state.
// LDS swizzle (involution, rule #21): row r (128 B = 8 chunks of 16 B): slot c
// holds global chunk c ^ (r&7); staged via pre-swizzled GLOBAL source + linear
// LDS dest; ds_read at chunk (quad+4*ks) ^ (r&7) -> 2-way bank aliasing (free).
template<int KDIM>
__device__ __forceinline__ void g256_stage(const u16* gA, const u16* gB, u16* sm,
                                           int buf, int t, int half, int wave8) {
    if (half < 2) {
#pragma unroll
        for (int i = 0; i < 2; ++i)
            load_lds16(gA + (size_t)(half * 128 + i * 64) * KDIM + t * 64,
                       sm + (buf * 2 + 0) * 16384 + (half * 128 + i * 64 + wave8) * 64);
    } else {
        int h = half - 2;
#pragma unroll
        for (int i = 0; i < 2; ++i)
            load_lds16(gB + (size_t)(h * 128 + i * 64) * KDIM + t * 64,
                       sm + (buf * 2 + 1) * 16384 + (h * 128 + i * 64 + wave8) * 64);
    }
}

template<int MH, int NH, bool READB, bool ENDBAR>
__device__ __forceinline__ void g256_phase(const u16* As, const u16* Bs,
                                           floatx4 (&acc)[8][4], short8 (&bfr)[2][2],
                                           int WR, int WC, int quad, int l15, int l7) {
    short8 afr[4][2];
#pragma unroll
    for (int mf = 0; mf < 4; ++mf)
#pragma unroll
        for (int ks = 0; ks < 2; ++ks)
            afr[mf][ks] = *reinterpret_cast<const short8*>(
                As + (WR * 128 + MH * 64 + mf * 16 + l15) * 64 + ((quad + 4 * ks) ^ l7) * 8);
    if (READB) {
#pragma unroll
        for (int nf = 0; nf < 2; ++nf)
#pragma unroll
            for (int ks = 0; ks < 2; ++ks)
                bfr[nf][ks] = *reinterpret_cast<const short8*>(
                    Bs + (WC * 64 + NH * 32 + nf * 16 + l15) * 64 + ((quad + 4 * ks) ^ l7) * 8);
    }
    barrier_mem();
    __builtin_amdgcn_s_setprio(1);
#pragma unroll
    for (int mf = 0; mf < 4; ++mf)
#pragma unroll
        for (int nf = 0; nf < 2; ++nf)
#pragma unroll
            for (int ks = 0; ks < 2; ++ks)
                acc[MH * 4 + mf][NH * 2 + nf] = __builtin_amdgcn_mfma_f32_16x16x32_bf16(
                    afr[mf][ks], bfr[nf][ks], acc[MH * 4 + mf][NH * 2 + nf], 0, 0, 0);
    __builtin_amdgcn_s_setprio(0);
    if (ENDBAR) barrier_mem();
}

template<int KDIM>
__global__ __launch_bounds__(512, 2)
void gemm256(const u16* __restrict__ A, const u16* __restrict__ B,
             u16* __restrict__ C, float scale)
{
    extern __shared__ u16 sm[];   // [buf][mat][256*64] = 128 KiB
    constexpr int NT = KDIM / 64;

    const int tid = threadIdx.x;
    const int lane = tid & 63, wave = tid >> 6;
    const int quad = lane >> 4, l15 = lane & 15, l7 = lane & 7;
    const int WR = wave >> 2, WC = wave & 3;
    const int wave8 = wave * 8;

    // XCD remap (grid = 256 blocks, 1/CU): 4 blocks sharing an A-stripe -> 1 XCD
    const int lin = blockIdx.x;
    const int xcd = lin & 7, j = lin >> 3;
    const int vbx = xcd * 8 + (j >> 2), vby = j & 3;
    const int bm = vbx * 256, bn = vby * 256;

    // staging source (pre-swizzled chunk): thread -> row wave*8+(lane>>3), chunk lane&7
    const int srow = wave8 + (lane >> 3);
    const int scg = (lane & 7) ^ ((lane >> 3) & 7);
    const u16* gA = A + (size_t)(bm + srow) * KDIM + scg * 8;
    const u16* gB = B + (size_t)(bn + srow) * KDIM + scg * 8;

    floatx4 acc[8][4];
#pragma unroll
    for (int mf = 0; mf < 8; ++mf)
#pragma unroll
        for (int nf = 0; nf < 4; ++nf)
#pragma unroll
            for (int r = 0; r < 4; ++r) acc[mf][nf][r] = 0.f;

    // prologue: tile0 fully, tile1 h0,h1  (12 instrs in flight)
#pragma unroll
    for (int h = 0; h < 4; ++h) g256_stage<KDIM>(gA, gB, sm, 0, 0, h, wave8);
    g256_stage<KDIM>(gA, gB, sm, 1, 1, 0, wave8);
    g256_stage<KDIM>(gA, gB, sm, 1, 1, 1, wave8);
    WAITVM(4);        // tile0 complete (oldest 8 drain), tile1.h0,h1 in flight
    barrier_mem();

    short8 bfr[2][2];
#pragma unroll 1
    for (int t = 0; t < NT; ++t) {
        const int cur = t & 1, nxt = cur ^ 1;
        const u16* As = sm + cur * 32768;
        const u16* Bs = As + 16384;

        // P0: quadrant (mh0,nh0); prefetch t+1.h2 (B-half0) into nxt
        if (t + 1 < NT) g256_stage<KDIM>(gA, gB, sm, nxt, t + 1, 2, wave8);
        g256_phase<0, 0, true,  true>(As, Bs, acc, bfr, WR, WC, quad, l15, l7);
        // P1: (mh1,nh0), B reused; prefetch t+1.h3
        if (t + 1 < NT) g256_stage<KDIM>(gA, gB, sm, nxt, t + 1, 3, wave8);
        g256_phase<1, 0, false, true>(As, Bs, acc, bfr, WR, WC, quad, l15, l7);
        // P2: (mh0,nh1)
        g256_phase<0, 1, true,  true>(As, Bs, acc, bfr, WR, WC, quad, l15, l7);
        // P3: (mh1,nh1), no end barrier: stage t+2.h0,h1 (into cur: all reads of
        // cur done before P3's mid-barrier), counted wait, then final barrier.
        g256_phase<1, 1, false, false>(As, Bs, acc, bfr, WR, WC, quad, l15, l7);
        if (t + 2 < NT) {
            g256_stage<KDIM>(gA, gB, sm, cur, t + 2, 0, wave8);
            g256_stage<KDIM>(gA, gB, sm, cur, t + 2, 1, wave8);
        }
        if (t + 1 < NT) {           // make tile t+1's buffer complete
            if (t + 2 < NT) WAITVM(4);
            else            WAITVM(0);
        }
        barrier_mem();
    }

    // epilogue: C/D frag col=l15, row=quad*4+r  [HW-verified]
#pragma unroll
    for (int mf = 0; mf < 8; ++mf)
#pragma unroll
        for (int nf = 0; nf < 4; ++nf)
#pragma unroll
            for (int r = 0; r < 4; ++r) {
                int row = bm + WR * 128 + mf * 16 + quad * 4 + r;
                int col = bn + WC * 64 + nf * 16 + l15;
                C[(size_t)row * 1024 + col] = f2bf(acc[mf][nf][r] * scale);
            }
}

// ---------------- GEMM: C[M,N] = A[M,K] @ B[N,K]^T  (fp32 acc) ------------------
// legacy 128x128 kernel (kept for V-TRANS, AO-POOL, and fallbacks)
#define GN 1024

template<int KDIM, bool SPLIT, bool TRANS, bool POOL, bool FP32A>
__global__ __launch_bounds__(256)
void gemm_bt(const void* __restrict__ Av, const u16* __restrict__ Bh,
             u16* __restrict__ Cb, float scale, u16* __restrict__ Vt,
             float* __restrict__ psum, float* __restrict__ pmax)
{
    constexpr int SM = TRANS ? 17408 : (FP32A ? 12288 : 8192);
    __shared__ __align__(16) u16 smem[SM];

    const int tid  = threadIdx.x;
    const int lane = tid & 63, wave = tid >> 6;
    const int quad = lane >> 4, l15 = lane & 15;
    const int wr = wave >> 1, wc = wave & 1;
    const int bm = blockIdx.x * 128, bn = blockIdx.y * 128;

    const int BOff = FP32A ? 8192 : 4096;   // u16 offset of B region

    floatx4 acc[4][4];
#pragma unroll
    for (int mt = 0; mt < 4; ++mt)
#pragma unroll
        for (int nt = 0; nt < 4; ++nt)
#pragma unroll
            for (int r = 0; r < 4; ++r) acc[mt][nt][r] = 0.f;

    const int s8 = (quad ^ ((l15 >> 1) & 3)) * 8;   // bf16 fragment chunk swizzle

    for (int kt = 0; kt < KDIM; kt += 32) {
        __syncthreads();
        if (FP32A) {
            const float* Af = (const float*)Av;
            const int arow = lane >> 3, achk = (lane & 7) ^ (lane >> 3);
            const int brow = lane >> 2, bchk = (lane & 3) ^ ((lane >> 3) & 3);
#pragma unroll
            for (int j = 0; j < 6; ++j) {
                int n = wave + 4 * j;
                if (n < 16) {
                    load_lds16(Af + (size_t)(bm + n * 8 + arow) * KDIM + kt + achk * 4,
                               smem + n * 512);
                } else {
                    int m = n - 16;
                    load_lds16(Bh + (size_t)(bn + m * 16 + brow) * KDIM + kt + bchk * 8,
                               smem + 8192 + m * 512);
                }
            }
        } else {
            const u16* Ab = (const u16*)Av;
            const int cgl = (lane & 3) ^ ((lane >> 3) & 3);
            const int rl  = lane >> 2;
            const u16* gp = (wave < 2) ? Ab : Bh;
            int rowb = (wave < 2) ? bm : bn;
            u16* lp = smem + (wave >> 1) * 4096;
            int q0 = (wave & 1) * 4;
#pragma unroll
            for (int q = 0; q < 4; ++q) {
                int qq = q0 + q;
                load_lds16(gp + (size_t)(rowb + qq * 16 + rl) * KDIM + cgl * 8 + kt,
                           lp + qq * 512);
            }
        }
        __syncthreads();

        short8 a_h[4], a_l[4], b_h[4];
        if (FP32A) {
            const float* Af4 = (const float*)smem;
#pragma unroll
            for (int mt = 0; mt < 4; ++mt) {
                int ra = wr * 64 + mt * 16 + l15;
                int f = ra & 7;
                float xv[8];
                *reinterpret_cast<float4*>(xv) =
                    *reinterpret_cast<const float4*>(Af4 + ra * 32 + (((2 * quad) ^ f) * 4));
                *reinterpret_cast<float4*>(xv + 4) =
                    *reinterpret_cast<const float4*>(Af4 + ra * 32 + (((2 * quad + 1) ^ f) * 4));
                if (SPLIT) cvt_split8(xv, a_h[mt], a_l[mt]);
                else       cvt_rne8(xv, a_h[mt]);
            }
        } else {
#pragma unroll
            for (int mt = 0; mt < 4; ++mt) {
                int ra = wr * 64 + mt * 16 + l15;
                a_h[mt] = *reinterpret_cast<const short8*>(smem + ra * 32 + s8);
            }
        }
#pragma unroll
        for (int nt = 0; nt < 4; ++nt) {
            int rb = wc * 64 + nt * 16 + l15;
            b_h[nt] = *reinterpret_cast<const short8*>(smem + BOff + rb * 32 + s8);
        }
#pragma unroll
        for (int mt = 0; mt < 4; ++mt)
#pragma unroll
            for (int nt = 0; nt < 4; ++nt)
                acc[mt][nt] = __builtin_amdgcn_mfma_f32_16x16x32_bf16(a_h[mt], b_h[nt], acc[mt][nt], 0, 0, 0);
        if (SPLIT) {
#pragma unroll
            for (int mt = 0; mt < 4; ++mt)
#pragma unroll
                for (int nt = 0; nt < 4; ++nt)
                    acc[mt][nt] = __builtin_amdgcn_mfma_f32_16x16x32_bf16(a_l[mt], b_h[nt], acc[mt][nt], 0, 0, 0);
        }
    }

    if (POOL) {
#pragma unroll
        for (int nt = 0; nt < 4; ++nt) {
            float s = 0.f, m = -3.0e38f;
#pragma unroll
            for (int mt = 0; mt < 4; ++mt)
#pragma unroll
                for (int r = 0; r < 4; ++r) {
                    float v = acc[mt][nt][r];
                    s += v; m = fmaxf(m, v);
                }
            s += __shfl_xor(s, 16); s += __shfl_xor(s, 32);
            m = fmaxf(m, __shfl_xor(m, 16)); m = fmaxf(m, __shfl_xor(m, 32));
            if (quad == 0) {
                int col = bn + wc * 64 + nt * 16 + l15;
                int chunk = (bm >> 6) + wr;   // rows bm+wr*64 .. +63
                psum[chunk * 1024 + col] = s;
                pmax[chunk * 1024 + col] = m;
            }
        }
    } else if (!TRANS) {
#pragma unroll
        for (int mt = 0; mt < 4; ++mt)
#pragma unroll
            for (int nt = 0; nt < 4; ++nt)
#pragma unroll
                for (int r = 0; r < 4; ++r) {
                    int row = bm + wr * 64 + mt * 16 + quad * 4 + r;
                    int col = bn + wc * 64 + nt * 16 + l15;
                    Cb[(size_t)row * GN + col] = f2bf(acc[mt][nt][r] * scale);
                }
    } else {
        __syncthreads();
#pragma unroll
        for (int mt = 0; mt < 4; ++mt)
#pragma unroll
            for (int nt = 0; nt < 4; ++nt)
#pragma unroll
                for (int r = 0; r < 4; ++r) {
                    int row_local = wr * 64 + mt * 16 + quad * 4 + r;
                    int col_local = wc * 64 + nt * 16 + l15;
                    smem[col_local * 136 + row_local] = f2bf(acc[mt][nt][r]);
                }
        __syncthreads();
        int b = bm >> 10, l0 = bm & 1023, h = bn >> 7;
        int d = tid >> 1, rblk = (tid & 1) * 64;
        u16* gv = Vt + ((size_t)(b * 8 + h) * 128 + d) * 1024 + l0 + rblk;
#pragma unroll
        for (int v = 0; v < 8; ++v)
            *reinterpret_cast<short8*>(gv + v * 8) =
                *reinterpret_cast<const short8*>(smem + d * 136 + rblk + v * 8);
    }
}

// ---------------- fused flash attention (no-max softmax, 32x32 MFMA) -------------
#define LOG2E 1.44269504088896f
#define EXPC  46.1662413084470f   // 32 * log2(e)

__global__ __launch_bounds__(256, 2)
void attn_kernel(const u16* __restrict__ Q, const u16* __restrict__ Kk,
                 const u16* __restrict__ Vt, u16* __restrict__ AO)
{
    __shared__ __align__(16) u16 Ks[2][64 * 128];    // [key][d], slot c = c ^ (key&7)
    __shared__ __align__(16) u16 Vts[2][128 * 64];   // [d][key], slot c = c ^ (d&7)

    const int tid  = threadIdx.x;
    const int lane = tid & 63, wave = tid >> 6;
    const int l31 = lane & 31, h2 = lane >> 5;
    const int l7 = lane & 7;

    const int lin = blockIdx.x + (blockIdx.y << 3) + (blockIdx.z << 6);
    const int qt = lin >> 7;
    const int hd = lin & 7;
    const int b  = (lin >> 3) & 15;

    short8 qf[8];
    {
        int qrow = b * 1024 + qt * 128 + wave * 32 + l31;
        const u16* qp = Q + (size_t)qrow * 1024 + hd * 128 + h2 * 8;
#pragma unroll
        for (int s = 0; s < 8; ++s)
            qf[s] = *reinterpret_cast<const short8*>(qp + s * 16);
    }

    float lsum = 0.f;
    floatx16 oacc[4];
#pragma unroll
    for (int db = 0; db < 4; ++db)
#pragma unroll
        for (int r = 0; r < 16; ++r) oacc[db][r] = 0.f;

    const int krow_l = lane >> 4;
    const u16* kgB[4];
#pragma unroll
    for (int i = 0; i < 4; ++i) {
        int cg = (lane & 15) ^ ((i * 4 + krow_l) & 7);
        kgB[i] = Kk + (size_t)(b * 1024 + wave * 16 + i * 4 + krow_l) * 1024
                    + hd * 128 + cg * 8;
    }
    const u16* vtb = Vt + (size_t)(b * 8 + hd) * 128 * 1024;
    const int vrow_l = lane >> 3;
    const u16* vgB = vtb + (size_t)(wave * 32 + vrow_l) * 1024
                         + (((lane & 7) ^ vrow_l) * 8);

#pragma unroll
    for (int i = 0; i < 4; ++i)
        load_lds16(kgB[i], &Ks[0][(wave * 16 + i * 4) * 128]);
#pragma unroll
    for (int i = 0; i < 4; ++i)
        load_lds16(vgB + (size_t)i * 8 * 1024, &Vts[0][(wave * 32 + i * 8) * 64]);

    for (int t = 0; t < 16; ++t) {
        const int cur = t & 1;
        asm volatile("s_waitcnt vmcnt(0)" ::: "memory");
        __builtin_amdgcn_s_barrier();
        __builtin_amdgcn_sched_barrier(0);
        if (t < 15) {
            const int nxt = cur ^ 1;
#pragma unroll
            for (int i = 0; i < 4; ++i)
                load_lds16(kgB[i] + (size_t)(t + 1) * 64 * 1024,
                           &Ks[nxt][(wave * 16 + i * 4) * 128]);
#pragma unroll
            for (int i = 0; i < 4; ++i)
                load_lds16(vgB + (size_t)i * 8 * 1024 + (size_t)(t + 1) * 64,
                           &Vts[nxt][(wave * 32 + i * 8) * 64]);
        }
        const u16* ksb = Ks[cur];
        const u16* vsb = Vts[cur];

        short8 pfr[4];
#pragma unroll
        for (int kb = 0; kb < 2; ++kb) {
            floatx16 sacc;
#pragma unroll
            for (int r = 0; r < 16; ++r) sacc[r] = 0.f;
            __builtin_amdgcn_s_setprio(1);
#pragma unroll
            for (int s = 0; s < 8; ++s) {
                short8 kfr = *reinterpret_cast<const short8*>(
                    &ksb[(kb * 32 + l31) * 128 + (((s * 2 + h2) ^ l7) * 8)]);
                sacc = __builtin_amdgcn_mfma_f32_32x32x16_bf16(kfr, qf[s], sacc, 0, 0, 0);
            }
            __builtin_amdgcn_s_setprio(0);
#pragma unroll
            for (int r = 0; r < 16; ++r) {
                float p = exp2f(fmaf(sacc[r], LOG2E, -EXPC));
                sacc[r] = p;
                lsum += p;
            }
            u32 c0[4], c1[4];
#pragma unroll
            for (int qd = 0; qd < 4; ++qd) {
                c0[qd] = cvtpk_bf16(sacc[4 * qd + 0], sacc[4 * qd + 1]);
                c1[qd] = cvtpk_bf16(sacc[4 * qd + 2], sacc[4 * qd + 3]);
            }
#pragma unroll
            for (int pb = 0; pb < 2; ++pb) {
                auto r1a = __builtin_amdgcn_permlane32_swap(c0[2 * pb],     c1[2 * pb],     false, false);
                auto r2a = __builtin_amdgcn_permlane32_swap(c1[2 * pb],     c0[2 * pb],     false, false);
                auto r1b = __builtin_amdgcn_permlane32_swap(c0[2 * pb + 1], c1[2 * pb + 1], false, false);
                auto r2b = __builtin_amdgcn_permlane32_swap(c1[2 * pb + 1], c0[2 * pb + 1], false, false);
                u32 w0 = h2 ? (u32)r2b[0] : (u32)r1a[0];
                u32 w1 = h2 ? (u32)r1b[0] : (u32)r2a[0];
                u32 w2 = h2 ? (u32)r2b[1] : (u32)r1a[1];
                u32 w3 = h2 ? (u32)r1b[1] : (u32)r2a[1];
                u32x4 ww = {w0, w1, w2, w3};
                pfr[kb * 2 + pb] = __builtin_bit_cast(short8, ww);
            }
        }

        __builtin_amdgcn_s_setprio(1);
#pragma unroll
        for (int ks = 0; ks < 4; ++ks) {
#pragma unroll
            for (int db = 0; db < 4; ++db) {
                int d = db * 32 + l31;
                short8 vfr = *reinterpret_cast<const short8*>(
                    &vsb[d * 64 + (((ks * 2 + h2) ^ l7) * 8)]);
                oacc[db] = __builtin_amdgcn_mfma_f32_32x32x16_bf16(pfr[ks], vfr, oacc[db], 0, 0, 0);
            }
        }
        __builtin_amdgcn_s_setprio(0);
    }

    lsum += __shfl_xor(lsum, 32);

    int qbase = b * 1024 + qt * 128 + wave * 32;
#pragma unroll
    for (int rg = 0; rg < 4; ++rg)
#pragma unroll
        for (int r = 0; r < 4; ++r) {
            int row = rg * 8 + 4 * h2 + r;
            float inv = 1.0f / __shfl(lsum, row);
            u16* ao = AO + (size_t)(qbase + row) * 1024 + hd * 128 + l31;
#pragma unroll
            for (int db = 0; db < 4; ++db)
                ao[db * 32] = f2bf(oacc[db][rg * 4 + r] * inv);
        }
}

// ---------------- fused pooling-combine + MLP head ------------------------------
__global__ __launch_bounds__(256)
void head_kernel(const float* __restrict__ psum, const float* __restrict__ pmax,
                 const float* __restrict__ bu, const float* __restrict__ Wmlp,
                 const float* __restrict__ bmlp, float* __restrict__ out) {
    __shared__ float pool_s[1024];
    int b = blockIdx.x, tid = threadIdx.x;
    int c4 = tid * 4;
    float4 s = {0.f, 0.f, 0.f, 0.f};
    float4 m = {-3.0e38f, -3.0e38f, -3.0e38f, -3.0e38f};
#pragma unroll
    for (int c = 0; c < 16; ++c) {
        float4 a = *reinterpret_cast<const float4*>(psum + (size_t)(b * 16 + c) * 1024 + c4);
        float4 x = *reinterpret_cast<const float4*>(pmax + (size_t)(b * 16 + c) * 1024 + c4);
        s.x += a.x; s.y += a.y; s.z += a.z; s.w += a.w;
        m.x = fmaxf(m.x, x.x); m.y = fmaxf(m.y, x.y);
        m.z = fmaxf(m.z, x.z); m.w = fmaxf(m.w, x.w);
    }
    float4 bb = *reinterpret_cast<const float4*>(bu + c4);
    pool_s[c4 + 0] = s.x * (1.0f / 1024.0f) + m.x + 2.0f * bb.x;
    pool_s[c4 + 1] = s.y * (1.0f / 1024.0f) + m.y + 2.0f * bb.y;
    pool_s[c4 + 2] = s.z * (1.0f / 1024.0f) + m.z + 2.0f * bb.z;
    pool_s[c4 + 3] = s.w * (1.0f / 1024.0f) + m.w + 2.0f * bb.w;
    __syncthreads();
    int o = tid >> 2, seg = tid & 3;
    const float4* wr = reinterpret_cast<const float4*>(Wmlp + o * 1024 + seg * 256);
    const float4* pr = reinterpret_cast<const float4*>(pool_s + seg * 256);
    float acc = 0.f;
#pragma unroll 8
    for (int i = 0; i < 64; ++i) {
        float4 a = pr[i], w = wr[i];
        acc += a.x * w.x + a.y * w.y + a.z * w.z + a.w * w.w;
    }
    acc += __shfl_xor(acc, 1);
    acc += __shfl_xor(acc, 2);
    if (seg == 0) out[b * 64 + o] = acc + bmlp[o];
}

extern "C" void kernel_launch(void* const* d_in, const int* in_sizes, int n_in,
                              void* d_out, int out_size, void* d_ws, size_t ws_size,
                              hipStream_t stream) {
    const float* x0 = (const float*)d_in[0];
    const float* x1 = (const float*)d_in[1];
    const float* x2 = (const float*)d_in[2];
    const float* Wk = (const float*)d_in[5];
    const float* Wq = (const float*)d_in[6];
    const float* Wv = (const float*)d_in[7];
    const float* Wu = (const float*)d_in[8];
    const float* bu = (const float*)d_in[9];
    const float* Wmlp = (const float*)d_in[10];
    const float* bmlp = (const float*)d_in[11];
    float* out = (float*)d_out;

    char* ws = (char*)d_ws;
    const size_t MB = 1048576ull;
    const float scale = 0.29730177875068026f;  // 128^(-0.25)

    // ---- main path (140 MB, same footprint/check as round 2) -------------------
    // [Wk2 0-4][Wq2 4-8][Wvh 8-10][Wuh 10-12][XS 12-76][Qb 76-108][Kb 108-140]
    // XS timeline: x2 split -> Q-GEMM; x1 split -> K-GEMM; Vt = ws+44 (32M);
    // AOb = ws+12 (32M). psum/pmax overlay Qb after attn.
    const size_t wo_new = 140 * MB;
    if (ws_size >= wo_new) {
        u16* Wk2 = (u16*)(ws);
        u16* Wq2 = (u16*)(ws + 4 * MB);
        u16* Wvh = (u16*)(ws + 8 * MB);
        u16* Wuh = (u16*)(ws + 10 * MB);
        u16* XS  = (u16*)(ws + 12 * MB);
        u16* Qb  = (u16*)(ws + 76 * MB);
        u16* Kb  = (u16*)(ws + 108 * MB);
        u16* Vt  = (u16*)(ws + 44 * MB);
        u16* AOb = XS;
        float* psum = (float*)Qb;
        float* pmax = (float*)((char*)Qb + 1 * MB);

        // enable 128 KiB dynamic LDS for the 8-phase GEMM; fall back if refused
        hipError_t attr_e = hipFuncSetAttribute(
            reinterpret_cast<const void*>(&gemm256<2048>),
            hipFuncAttributeMaxDynamicSharedMemorySize, 131072);
        const bool big = (attr_e == hipSuccess);

        convw_kernel<true><<<dim3(1024, 4), 256, 0, stream>>>(Wk, Wq, Wv, Wu, Wk2, Wq2, Wvh, Wuh);

        dim3 ggrid(128, 8);

        convx_kernel<true><<<16384, 256, 0, stream>>>(x2, XS);
        if (big) gemm256<2048><<<256, 512, 131072, stream>>>(XS, Wk2, Qb, scale);
        else     gemm_bt<2048, false, false, false, false><<<ggrid, 256, 0, stream>>>(XS, Wk2, Qb, scale, nullptr, nullptr, nullptr);

        convx_kernel<true><<<16384, 256, 0, stream>>>(x1, XS);
        if (big) gemm256<2048><<<256, 512, 131072, stream>>>(XS, Wq2, Kb, scale);
        else     gemm_bt<2048, false, false, false, false><<<ggrid, 256, 0, stream>>>(XS, Wq2, Kb, scale, nullptr, nullptr, nullptr);

        // v = x0 @ Wv^T (fp32-A in-loop rne, transposed write) — round-1 path
        gemm_bt<1024, false, true, false, true><<<ggrid, 256, 0, stream>>>(x0, Wvh, nullptr, 1.0f, Vt, nullptr, nullptr);

        dim3 agrid(8, 8, 16);
        attn_kernel<<<agrid, 256, 0, stream>>>(Qb, Kb, Vt, AOb);

        gemm_bt<1024, false, false, true, false><<<ggrid, 256, 0, stream>>>(AOb, Wuh, nullptr, 1.0f, nullptr, psum, pmax);

        head_kernel<<<16, 256, 0, stream>>>(psum, pmax, bu, Wmlp, bmlp, out);
        return;
    }

    // ---- fallback: round-1 path (138 MB) --------------------------------------
    const size_t MB32 = 33554432ull;
    size_t wo = 0;
    u16* Wkh = (u16*)(ws + wo); wo += 2097152;
    u16* Wqh = (u16*)(ws + wo); wo += 2097152;
    u16* Wvh = (u16*)(ws + wo); wo += 2097152;
    u16* Wuh = (u16*)(ws + wo); wo += 2097152;
    u16* Qb = (u16*)(ws + wo); wo += MB32;
    u16* Kb = (u16*)(ws + wo); wo += MB32;
    u16* Vt = (u16*)(ws + wo); wo += MB32;
    u16* AOb = (u16*)(ws + wo); wo += MB32;
    float* psum = (float*)(ws + wo); wo += 1048576;
    float* pmax = (float*)(ws + wo); wo += 1048576;
    if (ws_size < wo) return;

    convw_kernel<false><<<dim3(1024, 4), 256, 0, stream>>>(Wk, Wq, Wv, Wu, Wkh, Wqh, Wvh, Wuh);

    dim3 ggrid(128, 8);
    gemm_bt<1024, true, false, false, true><<<ggrid, 256, 0, stream>>>(x2, Wkh, Qb, scale, nullptr, nullptr, nullptr);
    gemm_bt<1024, true, false, false, true><<<ggrid, 256, 0, stream>>>(x1, Wqh, Kb, scale, nullptr, nullptr, nullptr);
    gemm_bt<1024, false, true, false, true><<<ggrid, 256, 0, stream>>>(x0, Wvh, nullptr, 1.0f, Vt, nullptr, nullptr);

    dim3 agrid(8, 8, 16);
    attn_kernel<<<agrid, 256, 0, stream>>>(Qb, Kb, Vt, AOb);

    gemm_bt<1024, false, false, true, false><<<ggrid, 256, 0, stream>>>(AOb, Wuh, nullptr, 1.0f, nullptr, psum, pmax);

    head_kernel<<<16, 256, 0, stream>>>(psum, pmax, bu, Wmlp, bmlp, out);
}

// Round 5
// 546.712 us; speedup vs baseline: 1.1509x; 1.0845x over previous
//
#include <hip/hip_runtime.h>

using u16 = unsigned short;
using u32 = unsigned int;
using short8 = __attribute__((ext_vector_type(8))) short;
using floatx4 = __attribute__((ext_vector_type(4))) float;
using floatx16 = __attribute__((ext_vector_type(16))) float;
using u32x4 = __attribute__((ext_vector_type(4))) u32;

__device__ __forceinline__ u32 fbits(float f) { union { float f; u32 u; } v; v.f = f; return v.u; }
__device__ __forceinline__ float fofb(u32 u) { union { u32 u; float f; } v; v.u = u; return v.f; }

__device__ __forceinline__ u16 f2bf(float f) {  // RNE
    u32 u = fbits(f);
    return (u16)((u + 0x7FFFu + ((u >> 16) & 1u)) >> 16);
}

// v_cvt_pk_bf16_f32: two fp32 -> packed 2xbf16 (RNE), lo=src0, hi=src1
__device__ __forceinline__ u32 cvtpk_bf16(float lo, float hi) {
    u32 r;
    asm("v_cvt_pk_bf16_f32 %0, %1, %2" : "=v"(r) : "v"(lo), "v"(hi));
    return r;
}

// split fp32 -> hi (truncated) + lo (residual, truncated); hi+lo error ~2^-17 rel
__device__ __forceinline__ void cvt_split8(const float* x, short8& h, short8& l) {
#pragma unroll
    for (int j = 0; j < 8; ++j) {
        u32 b = fbits(x[j]);
        h[j] = (short)(b >> 16);
        float r = x[j] - fofb(b & 0xffff0000u);
        l[j] = (short)(fbits(r) >> 16);
    }
}
__device__ __forceinline__ void cvt_rne8(const float* x, short8& h) {
#pragma unroll
    for (int j = 0; j < 8; ++j) h[j] = (short)f2bf(x[j]);
}

// async global->LDS, 16B per lane; LDS dest = wave-uniform base + lane*16
__device__ __forceinline__ void load_lds16(const void* g, u16* l) {
    __builtin_amdgcn_global_load_lds(
        (const __attribute__((address_space(1))) unsigned int*)(g),
        (__attribute__((address_space(3))) unsigned int*)(l), 16, 0, 0);
}

// raw barrier WITH memory clobber: orders all memory ops (ds_read, global_load_lds)
// across it but does NOT drain counters (unlike __syncthreads).
__device__ __forceinline__ void barrier_mem() {
    asm volatile("s_barrier" ::: "memory");
}
#define WAITVM(N) asm volatile("s_waitcnt vmcnt(" #N ")" ::: "memory")

// ---------------- weight conversions fp32 -> bf16, 4 matrices in one launch ----
// DUP: matrices 0,1 (Wk,Wq) written duplicated along K: W2[n][2048] = [W|W].
template<bool DUP>
__global__ void convw_kernel(const float* __restrict__ W0, const float* __restrict__ W1,
                             const float* __restrict__ W2, const float* __restrict__ W3,
                             u16* __restrict__ D0, u16* __restrict__ D1,
                             u16* __restrict__ D2, u16* __restrict__ D3) {
    int y = blockIdx.y;
    const float* s = (y == 0) ? W0 : (y == 1) ? W1 : (y == 2) ? W2 : W3;
    u16* d = (y == 0) ? D0 : (y == 1) ? D1 : (y == 2) ? D2 : D3;
    int i = (blockIdx.x * 256 + threadIdx.x) * 4;
    float4 v = *reinterpret_cast<const float4*>(s + i);
    ushort4 h;
    h.x = f2bf(v.x); h.y = f2bf(v.y); h.z = f2bf(v.z); h.w = f2bf(v.w);
    if (DUP && y < 2) {
        int n = i >> 10, k = i & 1023;
        u16* base = d + (size_t)n * 2048 + k;
        *reinterpret_cast<ushort4*>(base) = h;
        *reinterpret_cast<ushort4*>(base + 1024) = h;
    } else {
        *reinterpret_cast<ushort4*>(d + i) = h;
    }
}

// ---------------- activation conversion fp32 -> bf16 ---------------------------
// SPLIT: X[m][1024] fp32 -> O[m][2048] bf16, [0:1024]=hi(trunc), [1024:2048]=lo.
template<bool SPLIT>
__global__ __launch_bounds__(256)
void convx_kernel(const float* __restrict__ X, u16* __restrict__ O) {
    int i = (blockIdx.x * 256 + threadIdx.x) * 4;
    float4 v = *reinterpret_cast<const float4*>(X + i);
    if (SPLIT) {
        int m = i >> 10, k = i & 1023;
        float xs[4] = {v.x, v.y, v.z, v.w};
        ushort4 h, l;
        u16 hh[4], ll[4];
#pragma unroll
        for (int j = 0; j < 4; ++j) {
            u32 b = fbits(xs[j]);
            hh[j] = (u16)(b >> 16);
            float r = xs[j] - fofb(b & 0xffff0000u);
            ll[j] = (u16)(fbits(r) >> 16);
        }
        h.x = hh[0]; h.y = hh[1]; h.z = hh[2]; h.w = hh[3];
        l.x = ll[0]; l.y = ll[1]; l.z = ll[2]; l.w = ll[3];
        *reinterpret_cast<ushort4*>(O + (size_t)m * 2048 + k) = h;
        *reinterpret_cast<ushort4*>(O + (size_t)m * 2048 + 1024 + k) = l;
    } else {
        ushort4 h;
        h.x = f2bf(v.x); h.y = f2bf(v.y); h.z = f2bf(v.z); h.w = f2bf(v.w);
        *reinterpret_cast<ushort4*>(O + i) = h;
    }
}

// ================= 256x256 8-wave counted-vmcnt GEMM (T2+T3+T4+T5) ==============
// C[M,1024] = A[M,KDIM] @ B[1024,KDIM]^T, bf16 in, fp32 acc.
// 512 thr = 8 waves (2M x 4N), per-wave C = 128x64 (acc[8][4] 16x16 frags).
// LDS: dbuf x (A 256x64 + B 256x64) bf16 = 128 KiB (dynamic).
// MODE 0: C write (bf16, scaled).  MODE 1: Vt transposed write per (b,h) via LDS
// transpose (2 half-tile passes).  MODE 2: no C; per-column sum/max partials over
// the block's 256 rows into psum/pmax[128-row chunks].
// Stage protocol per K-tile (BK=64, 8 gload_lds/wave): t.P0 issues t+1.h2,
// t.P1 t+1.h3, t.P3 (post-MFMA) t+2.h0,h1 -> vmcnt(4) -> barrier. Queue at the
// wait: [t+1 x4 pairs(8), t+2 x2 pairs(4)] -> completes t+1 exactly; never
// drains to 0 in steady state (T4).
// LDS swizzle (involution): slot c of row r holds global chunk c ^ (r&7);
// pre-swizzled GLOBAL source + linear LDS dest; ds_read XORs the same -> 2-way.
template<int KDIM>
__device__ __forceinline__ void g256_stage(const u16* gA, const u16* gB, u16* sm,
                                           int buf, int t, int half, int wave8) {
    if (half < 2) {
#pragma unroll
        for (int i = 0; i < 2; ++i)
            load_lds16(gA + (size_t)(half * 128 + i * 64) * KDIM + t * 64,
                       sm + (buf * 2 + 0) * 16384 + (half * 128 + i * 64 + wave8) * 64);
    } else {
        int h = half - 2;
#pragma unroll
        for (int i = 0; i < 2; ++i)
            load_lds16(gB + (size_t)(h * 128 + i * 64) * KDIM + t * 64,
                       sm + (buf * 2 + 1) * 16384 + (h * 128 + i * 64 + wave8) * 64);
    }
}

template<int MH, int NH, bool READB, bool ENDBAR>
__device__ __forceinline__ void g256_phase(const u16* As, const u16* Bs,
                                           floatx4 (&acc)[8][4], short8 (&bfr)[2][2],
                                           int WR, int WC, int quad, int l15, int l7) {
    short8 afr[4][2];
#pragma unroll
    for (int mf = 0; mf < 4; ++mf)
#pragma unroll
        for (int ks = 0; ks < 2; ++ks)
            afr[mf][ks] = *reinterpret_cast<const short8*>(
                As + (WR * 128 + MH * 64 + mf * 16 + l15) * 64 + ((quad + 4 * ks) ^ l7) * 8);
    if (READB) {
#pragma unroll
        for (int nf = 0; nf < 2; ++nf)
#pragma unroll
            for (int ks = 0; ks < 2; ++ks)
                bfr[nf][ks] = *reinterpret_cast<const short8*>(
                    Bs + (WC * 64 + NH * 32 + nf * 16 + l15) * 64 + ((quad + 4 * ks) ^ l7) * 8);
    }
    barrier_mem();
    __builtin_amdgcn_s_setprio(1);
#pragma unroll
    for (int mf = 0; mf < 4; ++mf)
#pragma unroll
        for (int nf = 0; nf < 2; ++nf)
#pragma unroll
            for (int ks = 0; ks < 2; ++ks)
                acc[MH * 4 + mf][NH * 2 + nf] = __builtin_amdgcn_mfma_f32_16x16x32_bf16(
                    afr[mf][ks], bfr[nf][ks], acc[MH * 4 + mf][NH * 2 + nf], 0, 0, 0);
    __builtin_amdgcn_s_setprio(0);
    if (ENDBAR) barrier_mem();
}

template<int KDIM, int MODE>
__global__ __launch_bounds__(512, 2)
void gemm256(const u16* __restrict__ A, const u16* __restrict__ B,
             u16* __restrict__ C, float scale, u16* __restrict__ Vt,
             float* __restrict__ psum, float* __restrict__ pmax)
{
    extern __shared__ u16 sm[];   // [buf][mat][256*64] = 128 KiB
    constexpr int NT = KDIM / 64;

    const int tid = threadIdx.x;
    const int lane = tid & 63, wave = tid >> 6;
    const int quad = lane >> 4, l15 = lane & 15, l7 = lane & 7;
    const int WR = wave >> 2, WC = wave & 3;
    const int wave8 = wave * 8;

    // XCD remap (grid = 256 blocks, 1/CU): 4 blocks sharing an A-stripe -> 1 XCD
    const int lin = blockIdx.x;
    const int xcd = lin & 7, j = lin >> 3;
    const int vbx = xcd * 8 + (j >> 2), vby = j & 3;
    const int bm = vbx * 256, bn = vby * 256;

    // staging source (pre-swizzled chunk): thread -> row wave*8+(lane>>3), chunk lane&7
    const int srow = wave8 + (lane >> 3);
    const int scg = (lane & 7) ^ ((lane >> 3) & 7);
    const u16* gA = A + (size_t)(bm + srow) * KDIM + scg * 8;
    const u16* gB = B + (size_t)(bn + srow) * KDIM + scg * 8;

    floatx4 acc[8][4];
#pragma unroll
    for (int mf = 0; mf < 8; ++mf)
#pragma unroll
        for (int nf = 0; nf < 4; ++nf)
#pragma unroll
            for (int r = 0; r < 4; ++r) acc[mf][nf][r] = 0.f;

    // prologue: tile0 fully, tile1 h0,h1  (12 instrs in flight)
#pragma unroll
    for (int h = 0; h < 4; ++h) g256_stage<KDIM>(gA, gB, sm, 0, 0, h, wave8);
    g256_stage<KDIM>(gA, gB, sm, 1, 1, 0, wave8);
    g256_stage<KDIM>(gA, gB, sm, 1, 1, 1, wave8);
    WAITVM(4);        // tile0 complete (oldest 8 drain), tile1.h0,h1 in flight
    barrier_mem();

    short8 bfr[2][2];
#pragma unroll 1
    for (int t = 0; t < NT; ++t) {
        const int cur = t & 1, nxt = cur ^ 1;
        const u16* As = sm + cur * 32768;
        const u16* Bs = As + 16384;

        // P0: quadrant (mh0,nh0); prefetch t+1.h2 (B-half0) into nxt
        if (t + 1 < NT) g256_stage<KDIM>(gA, gB, sm, nxt, t + 1, 2, wave8);
        g256_phase<0, 0, true,  true>(As, Bs, acc, bfr, WR, WC, quad, l15, l7);
        // P1: (mh1,nh0), B reused; prefetch t+1.h3
        if (t + 1 < NT) g256_stage<KDIM>(gA, gB, sm, nxt, t + 1, 3, wave8);
        g256_phase<1, 0, false, true>(As, Bs, acc, bfr, WR, WC, quad, l15, l7);
        // P2: (mh0,nh1)
        g256_phase<0, 1, true,  true>(As, Bs, acc, bfr, WR, WC, quad, l15, l7);
        // P3: (mh1,nh1), no end barrier: stage t+2.h0,h1 (into cur: all reads of
        // cur done before P3's mid-barrier), counted wait, then final barrier.
        g256_phase<1, 1, false, false>(As, Bs, acc, bfr, WR, WC, quad, l15, l7);
        if (t + 2 < NT) {
            g256_stage<KDIM>(gA, gB, sm, cur, t + 2, 0, wave8);
            g256_stage<KDIM>(gA, gB, sm, cur, t + 2, 1, wave8);
        }
        if (t + 1 < NT) {           // make tile t+1's buffer complete
            if (t + 2 < NT) WAITVM(4);
            else            WAITVM(0);
        }
        barrier_mem();
    }

    if (MODE == 0) {
        // C/D frag col=l15, row=quad*4+r  [HW-verified]
#pragma unroll
        for (int mf = 0; mf < 8; ++mf)
#pragma unroll
            for (int nf = 0; nf < 4; ++nf)
#pragma unroll
                for (int r = 0; r < 4; ++r) {
                    int row = bm + WR * 128 + mf * 16 + quad * 4 + r;
                    int col = bn + WC * 64 + nf * 16 + l15;
                    C[(size_t)row * 1024 + col] = f2bf(acc[mf][nf][r] * scale);
                }
    } else if (MODE == 1) {
        // Vt[(b*8+h)*128 + d][l] transposed write, LDS-staged per 128-col pass.
        // LDS layout [col 0..127][row 0..255] pad-264 -> coalesced short8 stores.
        const int bb = bm >> 10, l0 = bm & 1023;
        const int d = tid >> 2, seg = tid & 3;
#pragma unroll
        for (int pass = 0; pass < 2; ++pass) {
            __syncthreads();
            if ((WC >> 1) == pass) {
#pragma unroll
                for (int mf = 0; mf < 8; ++mf)
#pragma unroll
                    for (int nf = 0; nf < 4; ++nf)
#pragma unroll
                        for (int r = 0; r < 4; ++r) {
                            int row_local = WR * 128 + mf * 16 + quad * 4 + r;
                            int col_local = (WC & 1) * 64 + nf * 16 + l15;
                            sm[col_local * 264 + row_local] = f2bf(acc[mf][nf][r]);
                        }
            }
            __syncthreads();
            int h = (bn >> 7) + pass;
            u16* gv = Vt + ((size_t)(bb * 8 + h) * 128 + d) * 1024 + l0 + seg * 64;
            const u16* ls = sm + d * 264 + seg * 64;
#pragma unroll
            for (int v = 0; v < 8; ++v)
                *reinterpret_cast<short8*>(gv + v * 8) =
                    *reinterpret_cast<const short8*>(ls + v * 8);
        }
    } else {
        // POOL: per-column sum/max over the block's 256 rows; 128-row chunks.
#pragma unroll
        for (int nf = 0; nf < 4; ++nf) {
            float s = 0.f, m = -3.0e38f;
#pragma unroll
            for (int mf = 0; mf < 8; ++mf)
#pragma unroll
                for (int r = 0; r < 4; ++r) {
                    float v = acc[mf][nf][r];
                    s += v; m = fmaxf(m, v);
                }
            s += __shfl_xor(s, 16); s += __shfl_xor(s, 32);
            m = fmaxf(m, __shfl_xor(m, 16)); m = fmaxf(m, __shfl_xor(m, 32));
            if (quad == 0) {
                int col = bn + WC * 64 + nf * 16 + l15;
                int chunk = (bm >> 7) + WR;   // rows bm+WR*128 .. +127
                psum[chunk * 1024 + col] = s;
                pmax[chunk * 1024 + col] = m;
            }
        }
    }
}

// ---------------- GEMM: C[M,N] = A[M,K] @ B[N,K]^T  (fp32 acc) ------------------
// legacy 128x128 kernel (fallback path only)
#define GN 1024

template<int KDIM, bool SPLIT, bool TRANS, bool POOL, bool FP32A>
__global__ __launch_bounds__(256)
void gemm_bt(const void* __restrict__ Av, const u16* __restrict__ Bh,
             u16* __restrict__ Cb, float scale, u16* __restrict__ Vt,
             float* __restrict__ psum, float* __restrict__ pmax)
{
    constexpr int SM = TRANS ? 17408 : (FP32A ? 12288 : 8192);
    __shared__ __align__(16) u16 smem[SM];

    const int tid  = threadIdx.x;
    const int lane = tid & 63, wave = tid >> 6;
    const int quad = lane >> 4, l15 = lane & 15;
    const int wr = wave >> 1, wc = wave & 1;
    const int bm = blockIdx.x * 128, bn = blockIdx.y * 128;

    const int BOff = FP32A ? 8192 : 4096;   // u16 offset of B region

    floatx4 acc[4][4];
#pragma unroll
    for (int mt = 0; mt < 4; ++mt)
#pragma unroll
        for (int nt = 0; nt < 4; ++nt)
#pragma unroll
            for (int r = 0; r < 4; ++r) acc[mt][nt][r] = 0.f;

    const int s8 = (quad ^ ((l15 >> 1) & 3)) * 8;   // bf16 fragment chunk swizzle

    for (int kt = 0; kt < KDIM; kt += 32) {
        __syncthreads();
        if (FP32A) {
            const float* Af = (const float*)Av;
            const int arow = lane >> 3, achk = (lane & 7) ^ (lane >> 3);
            const int brow = lane >> 2, bchk = (lane & 3) ^ ((lane >> 3) & 3);
#pragma unroll
            for (int j = 0; j < 6; ++j) {
                int n = wave + 4 * j;
                if (n < 16) {
                    load_lds16(Af + (size_t)(bm + n * 8 + arow) * KDIM + kt + achk * 4,
                               smem + n * 512);
                } else {
                    int m = n - 16;
                    load_lds16(Bh + (size_t)(bn + m * 16 + brow) * KDIM + kt + bchk * 8,
                               smem + 8192 + m * 512);
                }
            }
        } else {
            const u16* Ab = (const u16*)Av;
            const int cgl = (lane & 3) ^ ((lane >> 3) & 3);
            const int rl  = lane >> 2;
            const u16* gp = (wave < 2) ? Ab : Bh;
            int rowb = (wave < 2) ? bm : bn;
            u16* lp = smem + (wave >> 1) * 4096;
            int q0 = (wave & 1) * 4;
#pragma unroll
            for (int q = 0; q < 4; ++q) {
                int qq = q0 + q;
                load_lds16(gp + (size_t)(rowb + qq * 16 + rl) * KDIM + cgl * 8 + kt,
                           lp + qq * 512);
            }
        }
        __syncthreads();

        short8 a_h[4], a_l[4], b_h[4];
        if (FP32A) {
            const float* Af4 = (const float*)smem;
#pragma unroll
            for (int mt = 0; mt < 4; ++mt) {
                int ra = wr * 64 + mt * 16 + l15;
                int f = ra & 7;
                float xv[8];
                *reinterpret_cast<float4*>(xv) =
                    *reinterpret_cast<const float4*>(Af4 + ra * 32 + (((2 * quad) ^ f) * 4));
                *reinterpret_cast<float4*>(xv + 4) =
                    *reinterpret_cast<const float4*>(Af4 + ra * 32 + (((2 * quad + 1) ^ f) * 4));
                if (SPLIT) cvt_split8(xv, a_h[mt], a_l[mt]);
                else       cvt_rne8(xv, a_h[mt]);
            }
        } else {
#pragma unroll
            for (int mt = 0; mt < 4; ++mt) {
                int ra = wr * 64 + mt * 16 + l15;
                a_h[mt] = *reinterpret_cast<const short8*>(smem + ra * 32 + s8);
            }
        }
#pragma unroll
        for (int nt = 0; nt < 4; ++nt) {
            int rb = wc * 64 + nt * 16 + l15;
            b_h[nt] = *reinterpret_cast<const short8*>(smem + BOff + rb * 32 + s8);
        }
#pragma unroll
        for (int mt = 0; mt < 4; ++mt)
#pragma unroll
            for (int nt = 0; nt < 4; ++nt)
                acc[mt][nt] = __builtin_amdgcn_mfma_f32_16x16x32_bf16(a_h[mt], b_h[nt], acc[mt][nt], 0, 0, 0);
        if (SPLIT) {
#pragma unroll
            for (int mt = 0; mt < 4; ++mt)
#pragma unroll
                for (int nt = 0; nt < 4; ++nt)
                    acc[mt][nt] = __builtin_amdgcn_mfma_f32_16x16x32_bf16(a_l[mt], b_h[nt], acc[mt][nt], 0, 0, 0);
        }
    }

    if (POOL) {
#pragma unroll
        for (int nt = 0; nt < 4; ++nt) {
            float s = 0.f, m = -3.0e38f;
#pragma unroll
            for (int mt = 0; mt < 4; ++mt)
#pragma unroll
                for (int r = 0; r < 4; ++r) {
                    float v = acc[mt][nt][r];
                    s += v; m = fmaxf(m, v);
                }
            s += __shfl_xor(s, 16); s += __shfl_xor(s, 32);
            m = fmaxf(m, __shfl_xor(m, 16)); m = fmaxf(m, __shfl_xor(m, 32));
            if (quad == 0) {
                int col = bn + wc * 64 + nt * 16 + l15;
                int chunk = (bm >> 6) + wr;   // rows bm+wr*64 .. +63
                psum[chunk * 1024 + col] = s;
                pmax[chunk * 1024 + col] = m;
            }
        }
    } else if (!TRANS) {
#pragma unroll
        for (int mt = 0; mt < 4; ++mt)
#pragma unroll
            for (int nt = 0; nt < 4; ++nt)
#pragma unroll
                for (int r = 0; r < 4; ++r) {
                    int row = bm + wr * 64 + mt * 16 + quad * 4 + r;
                    int col = bn + wc * 64 + nt * 16 + l15;
                    Cb[(size_t)row * GN + col] = f2bf(acc[mt][nt][r] * scale);
                }
    } else {
        __syncthreads();
#pragma unroll
        for (int mt = 0; mt < 4; ++mt)
#pragma unroll
            for (int nt = 0; nt < 4; ++nt)
#pragma unroll
                for (int r = 0; r < 4; ++r) {
                    int row_local = wr * 64 + mt * 16 + quad * 4 + r;
                    int col_local = wc * 64 + nt * 16 + l15;
                    smem[col_local * 136 + row_local] = f2bf(acc[mt][nt][r]);
                }
        __syncthreads();
        int b = bm >> 10, l0 = bm & 1023, h = bn >> 7;
        int d = tid >> 1, rblk = (tid & 1) * 64;
        u16* gv = Vt + ((size_t)(b * 8 + h) * 128 + d) * 1024 + l0 + rblk;
#pragma unroll
        for (int v = 0; v < 8; ++v)
            *reinterpret_cast<short8*>(gv + v * 8) =
                *reinterpret_cast<const short8*>(smem + d * 136 + rblk + v * 8);
    }
}

// ---------------- fused flash attention (no-max softmax, 32x32 MFMA) -------------
#define LOG2E 1.44269504088896f
#define EXPC  46.1662413084470f   // 32 * log2(e)

__global__ __launch_bounds__(256, 2)
void attn_kernel(const u16* __restrict__ Q, const u16* __restrict__ Kk,
                 const u16* __restrict__ Vt, u16* __restrict__ AO)
{
    __shared__ __align__(16) u16 Ks[2][64 * 128];    // [key][d], slot c = c ^ (key&7)
    __shared__ __align__(16) u16 Vts[2][128 * 64];   // [d][key], slot c = c ^ (d&7)

    const int tid  = threadIdx.x;
    const int lane = tid & 63, wave = tid >> 6;
    const int l31 = lane & 31, h2 = lane >> 5;
    const int l7 = lane & 7;

    const int lin = blockIdx.x + (blockIdx.y << 3) + (blockIdx.z << 6);
    const int qt = lin >> 7;
    const int hd = lin & 7;
    const int b  = (lin >> 3) & 15;

    short8 qf[8];
    {
        int qrow = b * 1024 + qt * 128 + wave * 32 + l31;
        const u16* qp = Q + (size_t)qrow * 1024 + hd * 128 + h2 * 8;
#pragma unroll
        for (int s = 0; s < 8; ++s)
            qf[s] = *reinterpret_cast<const short8*>(qp + s * 16);
    }

    float lsum = 0.f;
    floatx16 oacc[4];
#pragma unroll
    for (int db = 0; db < 4; ++db)
#pragma unroll
        for (int r = 0; r < 16; ++r) oacc[db][r] = 0.f;

    const int krow_l = lane >> 4;
    const u16* kgB[4];
#pragma unroll
    for (int i = 0; i < 4; ++i) {
        int cg = (lane & 15) ^ ((i * 4 + krow_l) & 7);
        kgB[i] = Kk + (size_t)(b * 1024 + wave * 16 + i * 4 + krow_l) * 1024
                    + hd * 128 + cg * 8;
    }
    const u16* vtb = Vt + (size_t)(b * 8 + hd) * 128 * 1024;
    const int vrow_l = lane >> 3;
    const u16* vgB = vtb + (size_t)(wave * 32 + vrow_l) * 1024
                         + (((lane & 7) ^ vrow_l) * 8);

#pragma unroll
    for (int i = 0; i < 4; ++i)
        load_lds16(kgB[i], &Ks[0][(wave * 16 + i * 4) * 128]);
#pragma unroll
    for (int i = 0; i < 4; ++i)
        load_lds16(vgB + (size_t)i * 8 * 1024, &Vts[0][(wave * 32 + i * 8) * 64]);

    for (int t = 0; t < 16; ++t) {
        const int cur = t & 1;
        asm volatile("s_waitcnt vmcnt(0)" ::: "memory");
        __builtin_amdgcn_s_barrier();
        __builtin_amdgcn_sched_barrier(0);
        if (t < 15) {
            const int nxt = cur ^ 1;
#pragma unroll
            for (int i = 0; i < 4; ++i)
                load_lds16(kgB[i] + (size_t)(t + 1) * 64 * 1024,
                           &Ks[nxt][(wave * 16 + i * 4) * 128]);
#pragma unroll
            for (int i = 0; i < 4; ++i)
                load_lds16(vgB + (size_t)i * 8 * 1024 + (size_t)(t + 1) * 64,
                           &Vts[nxt][(wave * 32 + i * 8) * 64]);
        }
        const u16* ksb = Ks[cur];
        const u16* vsb = Vts[cur];

        short8 pfr[4];
#pragma unroll
        for (int kb = 0; kb < 2; ++kb) {
            floatx16 sacc;
#pragma unroll
            for (int r = 0; r < 16; ++r) sacc[r] = 0.f;
            __builtin_amdgcn_s_setprio(1);
#pragma unroll
            for (int s = 0; s < 8; ++s) {
                short8 kfr = *reinterpret_cast<const short8*>(
                    &ksb[(kb * 32 + l31) * 128 + (((s * 2 + h2) ^ l7) * 8)]);
                sacc = __builtin_amdgcn_mfma_f32_32x32x16_bf16(kfr, qf[s], sacc, 0, 0, 0);
            }
            __builtin_amdgcn_s_setprio(0);
#pragma unroll
            for (int r = 0; r < 16; ++r) {
                float p = exp2f(fmaf(sacc[r], LOG2E, -EXPC));
                sacc[r] = p;
                lsum += p;
            }
            u32 c0[4], c1[4];
#pragma unroll
            for (int qd = 0; qd < 4; ++qd) {
                c0[qd] = cvtpk_bf16(sacc[4 * qd + 0], sacc[4 * qd + 1]);
                c1[qd] = cvtpk_bf16(sacc[4 * qd + 2], sacc[4 * qd + 3]);
            }
#pragma unroll
            for (int pb = 0; pb < 2; ++pb) {
                auto r1a = __builtin_amdgcn_permlane32_swap(c0[2 * pb],     c1[2 * pb],     false, false);
                auto r2a = __builtin_amdgcn_permlane32_swap(c1[2 * pb],     c0[2 * pb],     false, false);
                auto r1b = __builtin_amdgcn_permlane32_swap(c0[2 * pb + 1], c1[2 * pb + 1], false, false);
                auto r2b = __builtin_amdgcn_permlane32_swap(c1[2 * pb + 1], c0[2 * pb + 1], false, false);
                u32 w0 = h2 ? (u32)r2b[0] : (u32)r1a[0];
                u32 w1 = h2 ? (u32)r1b[0] : (u32)r2a[0];
                u32 w2 = h2 ? (u32)r2b[1] : (u32)r1a[1];
                u32 w3 = h2 ? (u32)r1b[1] : (u32)r2a[1];
                u32x4 ww = {w0, w1, w2, w3};
                pfr[kb * 2 + pb] = __builtin_bit_cast(short8, ww);
            }
        }

        __builtin_amdgcn_s_setprio(1);
#pragma unroll
        for (int ks = 0; ks < 4; ++ks) {
#pragma unroll
            for (int db = 0; db < 4; ++db) {
                int d = db * 32 + l31;
                short8 vfr = *reinterpret_cast<const short8*>(
                    &vsb[d * 64 + (((ks * 2 + h2) ^ l7) * 8)]);
                oacc[db] = __builtin_amdgcn_mfma_f32_32x32x16_bf16(pfr[ks], vfr, oacc[db], 0, 0, 0);
            }
        }
        __builtin_amdgcn_s_setprio(0);
    }

    lsum += __shfl_xor(lsum, 32);

    int qbase = b * 1024 + qt * 128 + wave * 32;
#pragma unroll
    for (int rg = 0; rg < 4; ++rg)
#pragma unroll
        for (int r = 0; r < 4; ++r) {
            int row = rg * 8 + 4 * h2 + r;
            float inv = 1.0f / __shfl(lsum, row);
            u16* ao = AO + (size_t)(qbase + row) * 1024 + hd * 128 + l31;
#pragma unroll
            for (int db = 0; db < 4; ++db)
                ao[db * 32] = f2bf(oacc[db][rg * 4 + r] * inv);
        }
}

// ---------------- fused pooling-combine + MLP head ------------------------------
// nch: number of row-chunks per batch in psum/pmax (8 for gemm256, 16 for legacy)
__global__ __launch_bounds__(256)
void head_kernel(const float* __restrict__ psum, const float* __restrict__ pmax,
                 const float* __restrict__ bu, const float* __restrict__ Wmlp,
                 const float* __restrict__ bmlp, float* __restrict__ out, int nch) {
    __shared__ float pool_s[1024];
    int b = blockIdx.x, tid = threadIdx.x;
    int c4 = tid * 4;
    float4 s = {0.f, 0.f, 0.f, 0.f};
    float4 m = {-3.0e38f, -3.0e38f, -3.0e38f, -3.0e38f};
    for (int c = 0; c < nch; ++c) {
        float4 a = *reinterpret_cast<const float4*>(psum + (size_t)(b * nch + c) * 1024 + c4);
        float4 x = *reinterpret_cast<const float4*>(pmax + (size_t)(b * nch + c) * 1024 + c4);
        s.x += a.x; s.y += a.y; s.z += a.z; s.w += a.w;
        m.x = fmaxf(m.x, x.x); m.y = fmaxf(m.y, x.y);
        m.z = fmaxf(m.z, x.z); m.w = fmaxf(m.w, x.w);
    }
    float4 bb = *reinterpret_cast<const float4*>(bu + c4);
    pool_s[c4 + 0] = s.x * (1.0f / 1024.0f) + m.x + 2.0f * bb.x;
    pool_s[c4 + 1] = s.y * (1.0f / 1024.0f) + m.y + 2.0f * bb.y;
    pool_s[c4 + 2] = s.z * (1.0f / 1024.0f) + m.z + 2.0f * bb.z;
    pool_s[c4 + 3] = s.w * (1.0f / 1024.0f) + m.w + 2.0f * bb.w;
    __syncthreads();
    int o = tid >> 2, seg = tid & 3;
    const float4* wr = reinterpret_cast<const float4*>(Wmlp + o * 1024 + seg * 256);
    const float4* pr = reinterpret_cast<const float4*>(pool_s + seg * 256);
    float acc = 0.f;
#pragma unroll 8
    for (int i = 0; i < 64; ++i) {
        float4 a = pr[i], w = wr[i];
        acc += a.x * w.x + a.y * w.y + a.z * w.z + a.w * w.w;
    }
    acc += __shfl_xor(acc, 1);
    acc += __shfl_xor(acc, 2);
    if (seg == 0) out[b * 64 + o] = acc + bmlp[o];
}

extern "C" void kernel_launch(void* const* d_in, const int* in_sizes, int n_in,
                              void* d_out, int out_size, void* d_ws, size_t ws_size,
                              hipStream_t stream) {
    const float* x0 = (const float*)d_in[0];
    const float* x1 = (const float*)d_in[1];
    const float* x2 = (const float*)d_in[2];
    const float* Wk = (const float*)d_in[5];
    const float* Wq = (const float*)d_in[6];
    const float* Wv = (const float*)d_in[7];
    const float* Wu = (const float*)d_in[8];
    const float* bu = (const float*)d_in[9];
    const float* Wmlp = (const float*)d_in[10];
    const float* bmlp = (const float*)d_in[11];
    float* out = (float*)d_out;

    char* ws = (char*)d_ws;
    const size_t MB = 1048576ull;
    const float scale = 0.29730177875068026f;  // 128^(-0.25)

    // ---- main path (140 MB) ----------------------------------------------------
    // [Wk2 0-4][Wq2 4-8][Wvh 8-10][Wuh 10-12][XS 12-76][Qb 76-108][Kb 108-140]
    // XS timeline: x2 split (12-76) -> Q; x1 split -> K; x0h (12-44) -> V-GEMM
    // writes Vt (44-76); attn writes AOb (12-44, over x0h); psum/pmax overlay Qb.
    const size_t wo_new = 140 * MB;
    if (ws_size >= wo_new) {
        u16* Wk2 = (u16*)(ws);
        u16* Wq2 = (u16*)(ws + 4 * MB);
        u16* Wvh = (u16*)(ws + 8 * MB);
        u16* Wuh = (u16*)(ws + 10 * MB);
        u16* XS  = (u16*)(ws + 12 * MB);
        u16* Qb  = (u16*)(ws + 76 * MB);
        u16* Kb  = (u16*)(ws + 108 * MB);
        u16* Vt  = (u16*)(ws + 44 * MB);
        u16* AOb = XS;
        float* psum = (float*)Qb;
        float* pmax = (float*)((char*)Qb + 1 * MB);

        // enable 128 KiB dynamic LDS for the gemm256 variants; fall back if refused
        hipError_t e0 = hipFuncSetAttribute(
            reinterpret_cast<const void*>(&gemm256<2048, 0>),
            hipFuncAttributeMaxDynamicSharedMemorySize, 131072);
        hipError_t e1 = hipFuncSetAttribute(
            reinterpret_cast<const void*>(&gemm256<1024, 1>),
            hipFuncAttributeMaxDynamicSharedMemorySize, 131072);
        hipError_t e2 = hipFuncSetAttribute(
            reinterpret_cast<const void*>(&gemm256<1024, 2>),
            hipFuncAttributeMaxDynamicSharedMemorySize, 131072);
        const bool big = (e0 == hipSuccess && e1 == hipSuccess && e2 == hipSuccess);

        convw_kernel<true><<<dim3(1024, 4), 256, 0, stream>>>(Wk, Wq, Wv, Wu, Wk2, Wq2, Wvh, Wuh);

        if (big) {
            // q = (x2 @ Wk^T)*scale ; k = (x1 @ Wq^T)*scale  (pre-split K=2048)
            convx_kernel<true><<<16384, 256, 0, stream>>>(x2, XS);
            gemm256<2048, 0><<<256, 512, 131072, stream>>>(XS, Wk2, Qb, scale, nullptr, nullptr, nullptr);
            convx_kernel<true><<<16384, 256, 0, stream>>>(x1, XS);
            gemm256<2048, 0><<<256, 512, 131072, stream>>>(XS, Wq2, Kb, scale, nullptr, nullptr, nullptr);

            // v = x0 @ Wv^T, transposed write per (b,h)  (pre-converted bf16 A)
            convx_kernel<false><<<16384, 256, 0, stream>>>(x0, XS);
            gemm256<1024, 1><<<256, 512, 131072, stream>>>(XS, Wvh, nullptr, 1.0f, Vt, nullptr, nullptr);

            dim3 agrid(8, 8, 16);
            attn_kernel<<<agrid, 256, 0, stream>>>(Qb, Kb, Vt, AOb);

            // out = attn_out @ Wu^T, fused mean/max partials (128-row chunks)
            gemm256<1024, 2><<<256, 512, 131072, stream>>>(AOb, Wuh, nullptr, 1.0f, nullptr, psum, pmax);

            head_kernel<<<16, 256, 0, stream>>>(psum, pmax, bu, Wmlp, bmlp, out, 8);
        } else {
            dim3 ggrid(128, 8);
            convx_kernel<true><<<16384, 256, 0, stream>>>(x2, XS);
            gemm_bt<2048, false, false, false, false><<<ggrid, 256, 0, stream>>>(XS, Wk2, Qb, scale, nullptr, nullptr, nullptr);
            convx_kernel<true><<<16384, 256, 0, stream>>>(x1, XS);
            gemm_bt<2048, false, false, false, false><<<ggrid, 256, 0, stream>>>(XS, Wq2, Kb, scale, nullptr, nullptr, nullptr);
            gemm_bt<1024, false, true, false, true><<<ggrid, 256, 0, stream>>>(x0, Wvh, nullptr, 1.0f, Vt, nullptr, nullptr);
            dim3 agrid(8, 8, 16);
            attn_kernel<<<agrid, 256, 0, stream>>>(Qb, Kb, Vt, AOb);
            gemm_bt<1024, false, false, true, false><<<ggrid, 256, 0, stream>>>(AOb, Wuh, nullptr, 1.0f, nullptr, psum, pmax);
            head_kernel<<<16, 256, 0, stream>>>(psum, pmax, bu, Wmlp, bmlp, out, 16);
        }
        return;
    }

    // ---- fallback: round-1 path (138 MB) --------------------------------------
    const size_t MB32 = 33554432ull;
    size_t wo = 0;
    u16* Wkh = (u16*)(ws + wo); wo += 2097152;
    u16* Wqh = (u16*)(ws + wo); wo += 2097152;
    u16* Wvh = (u16*)(ws + wo); wo += 2097152;
    u16* Wuh = (u16*)(ws + wo); wo += 2097152;
    u16* Qb = (u16*)(ws + wo); wo += MB32;
    u16* Kb = (u16*)(ws + wo); wo += MB32;
    u16* Vt = (u16*)(ws + wo); wo += MB32;
    u16* AOb = (u16*)(ws + wo); wo += MB32;
    float* psum = (float*)(ws + wo); wo += 1048576;
    float* pmax = (float*)(ws + wo); wo += 1048576;
    if (ws_size < wo) return;

    convw_kernel<false><<<dim3(1024, 4), 256, 0, stream>>>(Wk, Wq, Wv, Wu, Wkh, Wqh, Wvh, Wuh);

    dim3 ggrid(128, 8);
    gemm_bt<1024, true, false, false, true><<<ggrid, 256, 0, stream>>>(x2, Wkh, Qb, scale, nullptr, nullptr, nullptr);
    gemm_bt<1024, true, false, false, true><<<ggrid, 256, 0, stream>>>(x1, Wqh, Kb, scale, nullptr, nullptr, nullptr);
    gemm_bt<1024, false, true, false, true><<<ggrid, 256, 0, stream>>>(x0, Wvh, nullptr, 1.0f, Vt, nullptr, nullptr);

    dim3 agrid(8, 8, 16);
    attn_kernel<<<agrid, 256, 0, stream>>>(Qb, Kb, Vt, AOb);

    gemm_bt<1024, false, false, true, false><<<ggrid, 256, 0, stream>>>(AOb, Wuh, nullptr, 1.0f, nullptr, psum, pmax);

    head_kernel<<<16, 256, 0, stream>>>(psum, pmax, bu, Wmlp, bmlp, out, 16);
}